// Round 16
// baseline (599.603 us; speedup 1.0000x reference)
//
#include <hip/hip_runtime.h>
#include <math.h>

#define ROIN 116
#define NBZ 1024
#define LDF 128            // padded ROI-row length (floats / bf16)
#define SROW (ROIN*LDF)    // 14848: padded per-sample flat row
#define NROWS (NBZ*ROIN)   // 118784
#define ALPHA 0.1f
#define ACOEF 0.9f
#define BETAC 2
#define EPSBN 1e-5f
#define PZ 29              // proj1 split-K chunks (29*512 = 14848)
#define PCH 512
#define W1LD SROW
#define GX2 928            // NROWS/128 (512-thread GEMM blocks)
#define GX45 1856          // NROWS/64 (gemm45 blocks)
#define GRAMZ 24
#define GRAMKS 640         // 24*640 = 15360 >= 14848 (tail chunk = 128)
#define NTRI 36            // upper-tri 128x128 tiles of 8x8 grid

typedef __attribute__((ext_vector_type(8))) short bf16x8;
typedef __attribute__((ext_vector_type(4))) float f32x4;

__device__ __forceinline__ float leakyf(float v){ return v >= 0.f ? v : 0.2f*v; }

__device__ __forceinline__ short f2bf(float f){
    unsigned u = __builtin_bit_cast(unsigned, f);
    unsigned r = u + 0x7fffu + ((u >> 16) & 1u);   // RNE
    return (short)(r >> 16);
}
__device__ __forceinline__ float bf2f(short h){
    unsigned u = ((unsigned)(unsigned short)h) << 16;
    return __builtin_bit_cast(float, u);
}

// Column permutation for permuted emits: logical c -> stored (c&15)*8 + (c>>4).
// Inverse: stored kp -> logical (kp&7)*16 + (kp>>3).

// ---------------------------------------------------------------------------
// Weight pretranspose + bf16 hi/lo split. Small weights -> WT[128][128].
// PERM: permute K-dim to match permuted activations.
// ---------------------------------------------------------------------------
template<bool PERM>
__global__ void wt_conv(const float* __restrict__ W, short* __restrict__ hi,
                        short* __restrict__ lo, int K, int N)
{
    int idx = blockIdx.x * 256 + threadIdx.x;   // 16384
    int n = idx >> 7, kp = idx & 127;
    int k = PERM ? ((kp & 7) * 16 + (kp >> 3)) : kp;
    float v = (n < N && k < K) ? W[(size_t)k * N + n] : 0.f;
    short h = f2bf(v);
    hi[idx] = h;
    lo[idx] = f2bf(v - bf2f(h));
}

// proj_w1 [13456,116] -> WT1[128][14848] hi/lo; K permuted within each
// 128-block to match permuted-fp32 xf
__global__ void wt1_conv(const float* __restrict__ W, short* __restrict__ hi,
                         short* __restrict__ lo)
{
    int idx = blockIdx.x * 256 + threadIdx.x;   // 128*14848
    int n = idx / W1LD, k = idx - n * W1LD;
    int r = k >> 7, dp = k & 127;
    int d = (dp & 7) * 16 + (dp >> 3);
    float v = (n < ROIN && d < ROIN) ? W[(size_t)(r * ROIN + d) * ROIN + n] : 0.f;
    short h = f2bf(v);
    hi[idx] = h;
    lo[idx] = f2bf(v - bf2f(h));
}

// ---------------------------------------------------------------------------
// bf16x2 MFMA GEMM, 512 threads, 128 rows/block, LDS-staged weights (hi+lo).
// EPI: 1 bias, 3 leaky(bias), 4 X + leaky(bias)
// XTRA: 0 none (C layout [m][n], guarded n<LDC);
//       1 emit PERMUTED fp32 C [m][P(n)] + permuted bf16 C + row sumsq
// ---------------------------------------------------------------------------
template<int EPI, int XTRA, bool PADK>
__global__ __launch_bounds__(512) void mfma_gemm_w(
    const float* __restrict__ A, const short* __restrict__ wt_hi,
    const short* __restrict__ wt_lo, const float* __restrict__ bias,
    const float* __restrict__ X, float* __restrict__ C,
    short* __restrict__ bfout, float* __restrict__ rsq,
    int LDA, int LDC)
{
    __shared__ short whi[128][136];
    __shared__ short wlo[128][136];
    const int tid = threadIdx.x;
    {
        int r = tid >> 2, q = tid & 3;
        const short* sh = wt_hi + r * 128 + q * 32;
        const short* sl = wt_lo + r * 128 + q * 32;
        #pragma unroll
        for (int i = 0; i < 4; ++i) {
            *(bf16x8*)(&whi[r][q * 32 + i * 8]) = *(const bf16x8*)(sh + i * 8);
            *(bf16x8*)(&wlo[r][q * 32 + i * 8]) = *(const bf16x8*)(sl + i * 8);
        }
    }
    __syncthreads();
    const int wave = tid >> 6, lane = tid & 63;
    const int m0 = blockIdx.x * 128 + wave * 16;
    const int rl = lane & 15, g = lane >> 4;
    const float* Arow = A + (size_t)(m0 + rl) * LDA;
    float av[4][8];
    #pragma unroll
    for (int s = 0; s < 4; ++s) {
        const int kk = s * 32 + g * 8;
        if (PADK || kk + 8 <= ROIN) {
            float4 p = *(const float4*)(Arow + kk);
            float4 q = *(const float4*)(Arow + kk + 4);
            av[s][0]=p.x; av[s][1]=p.y; av[s][2]=p.z; av[s][3]=p.w;
            av[s][4]=q.x; av[s][5]=q.y; av[s][6]=q.z; av[s][7]=q.w;
        } else if (kk + 4 <= ROIN) {
            float4 p = *(const float4*)(Arow + kk);
            av[s][0]=p.x; av[s][1]=p.y; av[s][2]=p.z; av[s][3]=p.w;
            av[s][4]=0.f; av[s][5]=0.f; av[s][6]=0.f; av[s][7]=0.f;
        } else {
            #pragma unroll
            for (int j = 0; j < 8; ++j) av[s][j] = 0.f;
        }
    }
    f32x4 acc[8];
    #pragma unroll
    for (int nf = 0; nf < 8; ++nf) acc[nf] = (f32x4){0.f,0.f,0.f,0.f};
    #pragma unroll
    for (int s = 0; s < 4; ++s) {
        const int kk = s * 32 + g * 8;
        bf16x8 ah, al;
        #pragma unroll
        for (int j = 0; j < 8; ++j) {
            short h = f2bf(av[s][j]); ah[j] = h;
            al[j] = f2bf(av[s][j] - bf2f(h));
        }
        #pragma unroll
        for (int nf = 0; nf < 8; ++nf) {
            const bf16x8 bh = *(const bf16x8*)(&whi[nf * 16 + rl][kk]);
            const bf16x8 bl = *(const bf16x8*)(&wlo[nf * 16 + rl][kk]);
            acc[nf] = __builtin_amdgcn_mfma_f32_16x16x32_bf16(ah, bh, acc[nf], 0, 0, 0);
            acc[nf] = __builtin_amdgcn_mfma_f32_16x16x32_bf16(al, bh, acc[nf], 0, 0, 0);
            acc[nf] = __builtin_amdgcn_mfma_f32_16x16x32_bf16(ah, bl, acc[nf], 0, 0, 0);
        }
    }
    const int cm = g * 4;
    if (XTRA == 1) {
        float fv[4][8];
        bf16x8 bfv[4];
        float rq[4] = {0.f, 0.f, 0.f, 0.f};
        #pragma unroll
        for (int nf = 0; nf < 8; ++nf) {
            int n = nf * 16 + rl;
            float bb = (n < ROIN) ? bias[n] : 0.f;
            #pragma unroll
            for (int j = 0; j < 4; ++j) {
                int m = m0 + cm + j;
                float v = 0.f;
                if (n < ROIN) {
                    v = acc[nf][j] + bb;
                    if (EPI == 3) v = leakyf(v);
                    else if (EPI == 4) v = X[(size_t)m * LDA + n] + leakyf(v);
                }
                fv[j][nf] = v;
                bfv[j][nf] = f2bf(v);
                rq[j] += v * v;
            }
        }
        #pragma unroll
        for (int j = 0; j < 4; ++j) {
            float* cp = &C[(size_t)(m0 + cm + j) * LDF + rl * 8];
            *(float4*)cp       = (float4){fv[j][0], fv[j][1], fv[j][2], fv[j][3]};
            *(float4*)(cp + 4) = (float4){fv[j][4], fv[j][5], fv[j][6], fv[j][7]};
            *(bf16x8*)(&bfout[(size_t)(m0 + cm + j) * LDF + rl * 8]) = bfv[j];
        }
        #pragma unroll
        for (int j = 0; j < 4; ++j) {
            rq[j] += __shfl_xor(rq[j], 1);
            rq[j] += __shfl_xor(rq[j], 2);
            rq[j] += __shfl_xor(rq[j], 4);
            rq[j] += __shfl_xor(rq[j], 8);
        }
        if (rl == 0) {
            #pragma unroll
            for (int j = 0; j < 4; ++j) rsq[m0 + cm + j] = rq[j];
        }
    } else {
        #pragma unroll
        for (int nf = 0; nf < 8; ++nf) {
            int n = nf * 16 + rl;
            float bb = (n < ROIN) ? bias[n] : 0.f;
            #pragma unroll
            for (int j = 0; j < 4; ++j) {
                int m = m0 + cm + j;
                float v = 0.f;
                if (n < ROIN) {
                    v = acc[nf][j] + bb;
                    if (EPI == 3) v = leakyf(v);
                    else if (EPI == 4) v = X[(size_t)m * LDA + n] + leakyf(v);
                }
                if (n < LDC) C[(size_t)m * LDC + n] = v;
            }
        }
    }
}

// ---------------------------------------------------------------------------
// Gather-fused GEMM on bf16-permuted activations (pipelined gather).
// W-lo DROPPED (GCN stack tolerance): 2 MFMAs/step, half the weight LDS ->
// ~39 KB LDS -> 4 blocks/CU for latency hiding on the random gather.
// ---------------------------------------------------------------------------
template<int XTRA, bool FOLD>
__global__ __launch_bounds__(512, 4) void mfma_gemm_wg_h(
    const float* __restrict__ vals, const int* __restrict__ idxs,
    const short* __restrict__ feat, const float* __restrict__ sbP,
    const float* __restrict__ tbP,
    const short* __restrict__ wt_hi,
    const float* __restrict__ bias, short* __restrict__ outH,
    float* __restrict__ statp)
{
    __shared__ short whi[128][136];
    __shared__ float st[(XTRA == 2) ? 8 : 1][2][128];
    const int tid = threadIdx.x;
    {
        int r = tid >> 2, q = tid & 3;
        const short* sh = wt_hi + r * 128 + q * 32;
        #pragma unroll
        for (int i = 0; i < 4; ++i)
            *(bf16x8*)(&whi[r][q * 32 + i * 8]) = *(const bf16x8*)(sh + i * 8);
    }
    __syncthreads();
    const int wave = tid >> 6, lane = tid & 63;
    const int m0 = blockIdx.x * 128 + wave * 16;
    const int rl = lane & 15, g = lane >> 4;
    const int m = m0 + rl;
    const unsigned bz = (unsigned)m / 116u;
    const int r = m - (int)bz * 116;
    float vv[8]; const short* fp[8];
    #pragma unroll
    for (int k = 0; k < 8; ++k) {
        vv[k] = vals[bz * 8 + k];
        int ixk = idxs[bz * 8 + k];
        fp[k] = feat + ((size_t)ixk * 116 + r) * 128;
    }
    float wsum = 0.f;
    if (FOLD) {
        #pragma unroll
        for (int k = 0; k < 8; ++k) wsum += vv[k];
    }
    f32x4 acc[8];
    #pragma unroll
    for (int nf = 0; nf < 8; ++nf) acc[nf] = (f32x4){0.f,0.f,0.f,0.f};
    bf16x8 xb[8], xn[8];
    #pragma unroll
    for (int k = 0; k < 8; ++k) xb[k] = *(const bf16x8*)(fp[k] + g * 8);
    #pragma unroll
    for (int s = 0; s < 4; ++s) {
        const int kk = s * 32 + g * 8;
        if (s < 3) {
            #pragma unroll
            for (int k = 0; k < 8; ++k) xn[k] = *(const bf16x8*)(fp[k] + kk + 32);
        }
        float av[8] = {0.f,0.f,0.f,0.f,0.f,0.f,0.f,0.f};
        #pragma unroll
        for (int k = 0; k < 8; ++k) {
            const float vk = vv[k];
            #pragma unroll
            for (int j = 0; j < 8; ++j) av[j] = fmaf(vk, bf2f(xb[k][j]), av[j]);
        }
        if (FOLD) {
            #pragma unroll
            for (int j = 0; j < 8; ++j)
                av[j] = sbP[kk + j] * av[j] + wsum * tbP[kk + j];   // pads: 0*0+w*0=0
        }
        bf16x8 ah, al;
        #pragma unroll
        for (int j = 0; j < 8; ++j) {
            short h = f2bf(av[j]); ah[j] = h;
            al[j] = f2bf(av[j] - bf2f(h));
        }
        __builtin_amdgcn_s_setprio(1);
        #pragma unroll
        for (int nf = 0; nf < 8; ++nf) {
            const bf16x8 bh = *(const bf16x8*)(&whi[nf * 16 + rl][kk]);
            acc[nf] = __builtin_amdgcn_mfma_f32_16x16x32_bf16(ah, bh, acc[nf], 0, 0, 0);
            acc[nf] = __builtin_amdgcn_mfma_f32_16x16x32_bf16(al, bh, acc[nf], 0, 0, 0);
        }
        __builtin_amdgcn_s_setprio(0);
        #pragma unroll
        for (int k = 0; k < 8; ++k) xb[k] = xn[k];
    }
    const int cm = g * 4;
    bf16x8 bfv[4];
    #pragma unroll
    for (int nf = 0; nf < 8; ++nf) {
        int n = nf * 16 + rl;
        float c1 = 0.f, c2 = 0.f;
        float bb = (n < ROIN) ? bias[n] : 0.f;
        #pragma unroll
        for (int j = 0; j < 4; ++j) {
            float v = 0.f;
            if (n < ROIN) v = leakyf(acc[nf][j] + bb);
            bfv[j][nf] = f2bf(v);
            if (XTRA == 2) { c1 += v; c2 += v * v; }
        }
        if (XTRA == 2) {
            c1 += __shfl_xor(c1, 16); c1 += __shfl_xor(c1, 32);
            c2 += __shfl_xor(c2, 16); c2 += __shfl_xor(c2, 32);
            if (lane < 16) { st[wave][0][n & 127] = c1; st[wave][1][n & 127] = c2; }
        }
    }
    #pragma unroll
    for (int j = 0; j < 4; ++j)
        *(bf16x8*)(&outH[(size_t)(m0 + cm + j) * LDF + rl * 8]) = bfv[j];
    if (XTRA == 2) {
        __syncthreads();
        if (tid < 232) {
            int sel = tid < 116 ? 0 : 1;
            int c = sel ? tid - 116 : tid;
            float s = 0.f;
            #pragma unroll
            for (int wv = 0; wv < 8; ++wv) s += st[wv][sel][c];
            statp[(size_t)(sel * 116 + c) * GX2 + blockIdx.x] = s;
        }
    }
}

// ---------------------------------------------------------------------------
// bf16-A GEMM (gcn_w2): A = bf16 permuted rows; W-lo dropped -> 1 MFMA.
// C = A@W + bias (no leaky). Emits bf16-permuted out + BN1 stats.
// ---------------------------------------------------------------------------
__global__ __launch_bounds__(512) void mfma_gemm_bA(
    const short* __restrict__ A,
    const short* __restrict__ wt_hi,
    const float* __restrict__ bias, short* __restrict__ outH,
    float* __restrict__ statp)
{
    __shared__ short whi[128][136];
    __shared__ float st[8][2][128];
    const int tid = threadIdx.x;
    {
        int r = tid >> 2, q = tid & 3;
        const short* sh = wt_hi + r * 128 + q * 32;
        #pragma unroll
        for (int i = 0; i < 4; ++i)
            *(bf16x8*)(&whi[r][q * 32 + i * 8]) = *(const bf16x8*)(sh + i * 8);
    }
    __syncthreads();
    const int wave = tid >> 6, lane = tid & 63;
    const int m0 = blockIdx.x * 128 + wave * 16;
    const int rl = lane & 15, g = lane >> 4;
    const short* Arow = A + (size_t)(m0 + rl) * LDF;
    bf16x8 av[4];
    #pragma unroll
    for (int s = 0; s < 4; ++s) av[s] = *(const bf16x8*)(Arow + s * 32 + g * 8);
    f32x4 acc[8];
    #pragma unroll
    for (int nf = 0; nf < 8; ++nf) acc[nf] = (f32x4){0.f,0.f,0.f,0.f};
    #pragma unroll
    for (int s = 0; s < 4; ++s) {
        const int kk = s * 32 + g * 8;
        const bf16x8 ah = av[s];
        #pragma unroll
        for (int nf = 0; nf < 8; ++nf) {
            const bf16x8 bh = *(const bf16x8*)(&whi[nf * 16 + rl][kk]);
            acc[nf] = __builtin_amdgcn_mfma_f32_16x16x32_bf16(ah, bh, acc[nf], 0, 0, 0);
        }
    }
    const int cm = g * 4;
    bf16x8 bfv[4];
    #pragma unroll
    for (int nf = 0; nf < 8; ++nf) {
        int n = nf * 16 + rl;
        float c1 = 0.f, c2 = 0.f;
        float bb = (n < ROIN) ? bias[n] : 0.f;
        #pragma unroll
        for (int j = 0; j < 4; ++j) {
            float v = 0.f;
            if (n < ROIN) v = acc[nf][j] + bb;
            bfv[j][nf] = f2bf(v);
            c1 += v; c2 += v * v;
        }
        c1 += __shfl_xor(c1, 16); c1 += __shfl_xor(c1, 32);
        c2 += __shfl_xor(c2, 16); c2 += __shfl_xor(c2, 32);
        if (lane < 16) { st[wave][0][n & 127] = c1; st[wave][1][n & 127] = c2; }
    }
    #pragma unroll
    for (int j = 0; j < 4; ++j)
        *(bf16x8*)(&outH[(size_t)(m0 + cm + j) * LDF + rl * 8]) = bfv[j];
    __syncthreads();
    if (tid < 232) {
        int sel = tid < 116 ? 0 : 1;
        int c = sel ? tid - 116 : tid;
        float s = 0.f;
        #pragma unroll
        for (int wv = 0; wv < 8; ++wv) s += st[wv][sel][c];
        statp[(size_t)(sel * 116 + c) * GX2 + blockIdx.x] = s;
    }
}

// ---------------------------------------------------------------------------
// Gather-fused pair on bf16-permuted activations (W-lo dropped):
// C[NROWS][8] = leaky(leaky(BN-gath @ W5(perm) + b5) @ W6 + b6)
// ---------------------------------------------------------------------------
__global__ __launch_bounds__(256) void mfma_gemm45_wg_h(
    const float* __restrict__ vals, const int* __restrict__ idxs,
    const short* __restrict__ feat, const float* __restrict__ sbP,
    const float* __restrict__ tbP,
    const short* __restrict__ w5h,
    const float* __restrict__ b5,
    const short* __restrict__ w6h,
    const float* __restrict__ b6,
    float* __restrict__ C)
{
    __shared__ short s5h[64][136];
    __shared__ short s6h[16][136];
    __shared__ float c1s[4][16][76];
    const int tid = threadIdx.x;
    {
        int r = tid >> 2, q = tid & 3;
        const short* sh = w5h + r * 128 + q * 32;
        #pragma unroll
        for (int i = 0; i < 4; ++i)
            *(bf16x8*)(&s5h[r][q * 32 + i * 8]) = *(const bf16x8*)(sh + i * 8);
        if (tid < 64) {
            int r6 = tid >> 2, q6 = tid & 3;
            const short* sh6 = w6h + r6 * 128 + q6 * 32;
            #pragma unroll
            for (int i = 0; i < 4; ++i)
                *(bf16x8*)(&s6h[r6][q6 * 32 + i * 8]) = *(const bf16x8*)(sh6 + i * 8);
        }
    }
    __syncthreads();
    const int wave = tid >> 6, lane = tid & 63;
    const int m0 = blockIdx.x * 64 + wave * 16;
    const int rl = lane & 15, g = lane >> 4;
    const int m = m0 + rl;
    const unsigned bz = (unsigned)m / 116u;
    const int r = m - (int)bz * 116;
    float vv[8]; const short* fp[8];
    #pragma unroll
    for (int k = 0; k < 8; ++k) {
        vv[k] = vals[bz * 8 + k];
        int ixk = idxs[bz * 8 + k];
        fp[k] = feat + ((size_t)ixk * 116 + r) * 128;
    }
    float wsum = 0.f;
    #pragma unroll
    for (int k = 0; k < 8; ++k) wsum += vv[k];
    f32x4 acc[4];
    #pragma unroll
    for (int nf = 0; nf < 4; ++nf) acc[nf] = (f32x4){0.f,0.f,0.f,0.f};
    bf16x8 xb[8], xn[8];
    #pragma unroll
    for (int k = 0; k < 8; ++k) xb[k] = *(const bf16x8*)(fp[k] + g * 8);
    #pragma unroll
    for (int s = 0; s < 4; ++s) {
        const int kk = s * 32 + g * 8;
        if (s < 3) {
            #pragma unroll
            for (int k = 0; k < 8; ++k) xn[k] = *(const bf16x8*)(fp[k] + kk + 32);
        }
        float av[8] = {0.f,0.f,0.f,0.f,0.f,0.f,0.f,0.f};
        #pragma unroll
        for (int k = 0; k < 8; ++k) {
            const float vk = vv[k];
            #pragma unroll
            for (int j = 0; j < 8; ++j) av[j] = fmaf(vk, bf2f(xb[k][j]), av[j]);
        }
        #pragma unroll
        for (int j = 0; j < 8; ++j)
            av[j] = sbP[kk + j] * av[j] + wsum * tbP[kk + j];
        bf16x8 ah, al;
        #pragma unroll
        for (int j = 0; j < 8; ++j) {
            short h = f2bf(av[j]); ah[j] = h;
            al[j] = f2bf(av[j] - bf2f(h));
        }
        __builtin_amdgcn_s_setprio(1);
        #pragma unroll
        for (int nf = 0; nf < 4; ++nf) {
            const bf16x8 bh = *(const bf16x8*)(&s5h[nf * 16 + rl][kk]);
            acc[nf] = __builtin_amdgcn_mfma_f32_16x16x32_bf16(ah, bh, acc[nf], 0, 0, 0);
            acc[nf] = __builtin_amdgcn_mfma_f32_16x16x32_bf16(al, bh, acc[nf], 0, 0, 0);
        }
        __builtin_amdgcn_s_setprio(0);
        #pragma unroll
        for (int k = 0; k < 8; ++k) xb[k] = xn[k];
    }
    const int cm = g * 4;
    #pragma unroll
    for (int nf = 0; nf < 4; ++nf) {
        int n = nf * 16 + rl;   // < 64
        float bb = b5[n];
        #pragma unroll
        for (int j = 0; j < 4; ++j)
            c1s[wave][cm + j][n] = leakyf(acc[nf][j] + bb);
    }
    // phase 2: K=64, N=8 (wave-local LDS; unpermuted; A hi/lo kept, W-lo dropped)
    f32x4 acc2 = {0.f,0.f,0.f,0.f};
    #pragma unroll
    for (int s = 0; s < 2; ++s) {
        const int kk = s * 32 + g * 8;
        float4 p = *(const float4*)(&c1s[wave][rl][kk]);
        float4 q = *(const float4*)(&c1s[wave][rl][kk + 4]);
        float a2[8] = {p.x, p.y, p.z, p.w, q.x, q.y, q.z, q.w};
        bf16x8 ah, al;
        #pragma unroll
        for (int j = 0; j < 8; ++j) {
            short h = f2bf(a2[j]); ah[j] = h;
            al[j] = f2bf(a2[j] - bf2f(h));
        }
        const bf16x8 bh = *(const bf16x8*)(&s6h[rl][kk]);
        acc2 = __builtin_amdgcn_mfma_f32_16x16x32_bf16(ah, bh, acc2, 0, 0, 0);
        acc2 = __builtin_amdgcn_mfma_f32_16x16x32_bf16(al, bh, acc2, 0, 0, 0);
    }
    if (rl < 8) {
        float bb = b6[rl];
        #pragma unroll
        for (int j = 0; j < 4; ++j) {
            float v = leakyf(acc2[j] + bb);
            C[(size_t)(m0 + cm + j) * 8 + rl] = v;
        }
    }
}

// BN finalize (permuted out): sbP[P(c)] = rstd*g, tbP[P(c)] = b - mean*rstd*g
__global__ void bn_final_st_p(const float* __restrict__ statp, const float* __restrict__ g,
                              const float* __restrict__ bta, float* __restrict__ sbP,
                              float* __restrict__ tbP, int cnt)
{
    int c = blockIdx.x, tid = threadIdx.x;   // 128 x 256
    int pc = (c & 15) * 8 + (c >> 4);
    if (c >= ROIN) { if (tid == 0) { sbP[pc] = 0.f; tbP[pc] = 0.f; } return; }
    float a1 = 0.f, a2 = 0.f;
    for (int i = tid; i < cnt; i += 256) {
        a1 += statp[(size_t)c * cnt + i];
        a2 += statp[(size_t)(116 + c) * cnt + i];
    }
    __shared__ float r1[256], r2[256];
    r1[tid] = a1; r2[tid] = a2; __syncthreads();
    for (int off = 128; off > 0; off >>= 1) {
        if (tid < off) { r1[tid] += r1[tid + off]; r2[tid] += r2[tid + off]; }
        __syncthreads();
    }
    if (tid == 0) {
        float mean = r1[0] / (float)NROWS;
        float var = r2[0] / (float)NROWS - mean * mean;
        float rstd = 1.f / sqrtf(var + EPSBN);
        float s = rstd * g[c];
        sbP[pc] = s;
        tbP[pc] = bta[c] - mean * s;
    }
}

// sq[bz] = sum of 116 per-M-row sumsq partials
__global__ void sq_reduce(const float* __restrict__ rsq, float* __restrict__ sq)
{
    int i = blockIdx.x * 256 + threadIdx.x;
    if (i >= NBZ) return;
    const float* p = rsq + (size_t)i * ROIN;
    float s = 0.f;
    #pragma unroll 4
    for (int r = 0; r < ROIN; ++r) s += p[r];
    sq[i] = s;
}

// ---------------------------------------------------------------------------
// proj1 via bf16x2 MFMA, split-K over PERMUTED padded xf [1024][14848]
// ---------------------------------------------------------------------------
__global__ __launch_bounds__(256) void mfma_proj1(
    const float* __restrict__ A, const short* __restrict__ wt_hi,
    const short* __restrict__ wt_lo, float* __restrict__ part)
{
    const int wave = threadIdx.x >> 6, lane = threadIdx.x & 63;
    const int m0 = blockIdx.x * 64 + wave * 16;
    const int rl = lane & 15, g = lane >> 4;
    const int kbase = blockIdx.z * PCH;
    const float* Arow = A + (size_t)(m0 + rl) * SROW;
    f32x4 acc[8];
    #pragma unroll
    for (int nf = 0; nf < 8; ++nf) acc[nf] = (f32x4){0.f,0.f,0.f,0.f};
    for (int s = 0; s < 16; ++s) {
        const int kk = kbase + s * 32 + g * 8;
        float4 p = *(const float4*)(Arow + kk);
        float4 q = *(const float4*)(Arow + kk + 4);
        float av[8] = {p.x, p.y, p.z, p.w, q.x, q.y, q.z, q.w};
        bf16x8 ah, al;
        #pragma unroll
        for (int j = 0; j < 8; ++j) {
            short h = f2bf(av[j]); ah[j] = h;
            al[j] = f2bf(av[j] - bf2f(h));
        }
        #pragma unroll
        for (int nf = 0; nf < 8; ++nf) {
            size_t boff = (size_t)(nf * 16 + rl) * W1LD + kk;
            bf16x8 bh = *(const bf16x8*)(wt_hi + boff);
            bf16x8 bl = *(const bf16x8*)(wt_lo + boff);
            acc[nf] = __builtin_amdgcn_mfma_f32_16x16x32_bf16(ah, bh, acc[nf], 0, 0, 0);
            acc[nf] = __builtin_amdgcn_mfma_f32_16x16x32_bf16(al, bh, acc[nf], 0, 0, 0);
            acc[nf] = __builtin_amdgcn_mfma_f32_16x16x32_bf16(ah, bl, acc[nf], 0, 0, 0);
        }
    }
    float* Cb = part + (size_t)blockIdx.z * NBZ * ROIN;
    const int cm = g * 4;
    #pragma unroll
    for (int nf = 0; nf < 8; ++nf) {
        int n = nf * 16 + rl;
        if (n < ROIN) {
            #pragma unroll
            for (int j = 0; j < 4; ++j)
                Cb[(size_t)(m0 + cm + j) * ROIN + n] = acc[nf][j];
        }
    }
}

// split-K reduce for proj1 (+bias +relu)
__global__ void proj_reduce(const float* __restrict__ ppart,
                            const float* __restrict__ bias, float* __restrict__ t1)
{
    int e = blockIdx.x * 256 + threadIdx.x;
    if (e >= NBZ * ROIN) return;
    int n = e % ROIN;
    float s = 0.f;
    for (int z = 0; z < PZ; ++z) s += ppart[(size_t)z * NBZ * ROIN + e];
    t1[e] = fmaxf(s + bias[n], 0.f);
}

// ---------------------------------------------------------------------------
// fp32 GEMM NT (sim = pn @ pn^T, K=116), symmetric mirror write
// ---------------------------------------------------------------------------
__global__ __launch_bounds__(256) void gemm_nt_sym(
    const float* __restrict__ A, float* __restrict__ C, int M, int K, float scale)
{
    if ((int)blockIdx.y < (int)blockIdx.x) return;
    __shared__ float As[16][65];
    __shared__ float Bs[16][65];
    const int tid = threadIdx.x;
    const int m0 = blockIdx.x * 64;
    const int n0 = blockIdx.y * 64;
    const int tm4 = (tid >> 4) * 4;
    const int tn4 = (tid & 15) * 4;
    const int rA  = tid >> 2;
    const int kbA = (tid & 3) * 4;
    float acc[4][4] = {};
    for (int kt = 0; kt < K; kt += 16) {
        int kg = kt + kbA;
        if (kg + 4 <= K) {
            float4 va = *(const float4*)(A + (size_t)(m0 + rA) * K + kg);
            As[kbA + 0][rA] = va.x; As[kbA + 1][rA] = va.y;
            As[kbA + 2][rA] = va.z; As[kbA + 3][rA] = va.w;
            float4 vb = *(const float4*)(A + (size_t)(n0 + rA) * K + kg);
            Bs[kbA + 0][rA] = vb.x; Bs[kbA + 1][rA] = vb.y;
            Bs[kbA + 2][rA] = vb.z; Bs[kbA + 3][rA] = vb.w;
        } else {
            #pragma unroll
            for (int kk = 0; kk < 4; ++kk) {
                int kgg = kg + kk;
                As[kbA + kk][rA] = (kgg < K) ? A[(size_t)(m0 + rA) * K + kgg] : 0.f;
                Bs[kbA + kk][rA] = (kgg < K) ? A[(size_t)(n0 + rA) * K + kgg] : 0.f;
            }
        }
        __syncthreads();
        #pragma unroll
        for (int k = 0; k < 16; ++k) {
            float a[4], b[4];
            #pragma unroll
            for (int i = 0; i < 4; ++i) a[i] = As[k][tm4 + i];
            #pragma unroll
            for (int j = 0; j < 4; ++j) b[j] = Bs[k][tn4 + j];
            #pragma unroll
            for (int i = 0; i < 4; ++i)
                #pragma unroll
                for (int j = 0; j < 4; ++j)
                    acc[i][j] = fmaf(a[i], b[j], acc[i][j]);
        }
        __syncthreads();
    }
    #pragma unroll
    for (int i = 0; i < 4; ++i) {
        int m = m0 + tm4 + i;
        #pragma unroll
        for (int j = 0; j < 4; ++j) {
            int n = n0 + tn4 + j;
            float v = acc[i][j] * scale;
            C[(size_t)m * M + n] = v;
            C[(size_t)n * M + m] = v;
        }
    }
}

// ---------------------------------------------------------------------------
// Gram via bf16 MFMA over padded/permuted xfh. 1D grid 864 = 36 tri x 24 z,
// XCD-affine: wg = (id&7)*108 + (id>>3).
// ---------------------------------------------------------------------------
__global__ __launch_bounds__(256) void gram_mfma(
    const short* __restrict__ Xh, float* __restrict__ gpart)
{
    const int id = blockIdx.x;
    const int wg = (id & 7) * 108 + (id >> 3);
    const int z = wg / 36;
    const int tri = wg - z * 36;
    int bx = 0;
    #pragma unroll
    for (int b = 1; b < 8; ++b) {
        int base = b * 8 - (b * (b - 1)) / 2;
        if (base <= tri) bx = b;
    }
    const int by = tri - (bx * 8 - (bx * (bx - 1)) / 2) + bx;
    const int k0 = z * GRAMKS;
    const int k1 = (k0 + GRAMKS < SROW) ? (k0 + GRAMKS) : SROW;
    const int wave = threadIdx.x >> 6, lane = threadIdx.x & 63;
    const int wr = wave >> 1, wc = wave & 1;
    const int row = lane & 15, koff = (lane >> 4) * 8;
    const short* Ap[4]; const short* Bp[4];
    #pragma unroll
    for (int i = 0; i < 4; ++i) {
        Ap[i] = Xh + (size_t)(bx * 128 + wr * 64 + i * 16 + row) * SROW;
        Bp[i] = Xh + (size_t)(by * 128 + wc * 64 + i * 16 + row) * SROW;
    }
    f32x4 acc[4][4];
    #pragma unroll
    for (int i = 0; i < 4; ++i)
        #pragma unroll
        for (int j = 0; j < 4; ++j) acc[i][j] = (f32x4){0.f,0.f,0.f,0.f};
    bf16x8 a[4], b[4];
    {
        int kk = k0 + koff;
        #pragma unroll
        for (int i = 0; i < 4; ++i) {
            a[i] = *(const bf16x8*)(Ap[i] + kk);
            b[i] = *(const bf16x8*)(Bp[i] + kk);
        }
    }
    for (int k = k0 + 32; k < k1; k += 32) {
        bf16x8 an[4], bn[4];
        int kk = k + koff;
        #pragma unroll
        for (int i = 0; i < 4; ++i) {
            an[i] = *(const bf16x8*)(Ap[i] + kk);
            bn[i] = *(const bf16x8*)(Bp[i] + kk);
        }
        #pragma unroll
        for (int i = 0; i < 4; ++i)
            #pragma unroll
            for (int j = 0; j < 4; ++j)
                acc[i][j] = __builtin_amdgcn_mfma_f32_16x16x32_bf16(a[i], b[j], acc[i][j], 0, 0, 0);
        #pragma unroll
        for (int i = 0; i < 4; ++i) { a[i] = an[i]; b[i] = bn[i]; }
    }
    #pragma unroll
    for (int i = 0; i < 4; ++i)
        #pragma unroll
        for (int j = 0; j < 4; ++j)
            acc[i][j] = __builtin_amdgcn_mfma_f32_16x16x32_bf16(a[i], b[j], acc[i][j], 0, 0, 0);
    float* Cb = gpart + ((size_t)z * NTRI + tri) * 16384;
    const int crow = (lane >> 4) * 4;
    const int ccol = lane & 15;
    #pragma unroll
    for (int i = 0; i < 4; ++i) {
        #pragma unroll
        for (int j = 0; j < 4; ++j) {
            int cl = wc * 64 + j * 16 + ccol;
            #pragma unroll
            for (int jj = 0; jj < 4; ++jj) {
                int rl2 = wr * 64 + i * 16 + crow + jj;
                Cb[(size_t)rl2 * 128 + cl] = acc[i][j][jj];
            }
        }
    }
}

// reduce GRAMZ packed-tri partials -> fused dist (with mirror write)
__global__ void gram_reduce_dist(const float* __restrict__ gpart,
                                 const float* __restrict__ sim, const float* __restrict__ sq,
                                 const int* __restrict__ ages, const int* __restrict__ genders,
                                 const float* __restrict__ fscal, float* __restrict__ G)
{
    const int t = blockIdx.x;   // 0..35
    int bx = 0;
    #pragma unroll
    for (int b = 1; b < 8; ++b) {
        int base = b * 8 - (b * (b - 1)) / 2;
        if (base <= t) bx = b;
    }
    const int by = t - (bx * 8 - (bx * (bx - 1)) / 2) + bx;
    int e = blockIdx.y * 1024 + threadIdx.x * 4;
    float sx = 0.f, sy = 0.f, sz = 0.f, sw = 0.f;
    for (int z = 0; z < GRAMZ; ++z) {
        float4 v = *(const float4*)(gpart + ((size_t)z * NTRI + t) * 16384 + e);
        sx += v.x; sy += v.y; sz += v.z; sw += v.w;
    }
    const int i = bx * 128 + (e >> 7), j0 = by * 128 + (e & 127);
    const float smin = fscal[0], smax = fscal[1];
    const float inv = 1.f / (smax - smin);
    const float sqi = sq[i];
    const int agei = ages[i], geni = genders[i];
    float4 simv = *(const float4*)(sim + ((size_t)i << 10) + j0);
    float gs[4] = {sx, sy, sz, sw};
    float sms[4] = {simv.x, simv.y, simv.z, simv.w};
    float out[4];
    #pragma unroll
    for (int c = 0; c < 4; ++c) {
        int j = j0 + c;
        float sn = (sms[c] - smin) * inv;
        float d2 = fmaxf(sqi + sq[j] - 2.f * gs[c], 0.f);
        float fs = expf(-ALPHA * sqrtf(d2));
        float total = fs * (1.f - sn) + sn;
        int da = agei - ages[j]; if (da < 0) da = -da;
        bool cond = (da <= BETAC) && (geni == genders[j]);
        out[c] = total * (cond ? ACOEF : 1.f - ACOEF);
    }
    float4 o = {out[0], out[1], out[2], out[3]};
    *(float4*)(G + ((size_t)i << 10) + j0) = o;
    #pragma unroll
    for (int c = 0; c < 4; ++c)
        G[((size_t)(j0 + c) << 10) + i] = out[c];
}

// p[1024,116] -> row L2-normalize in place
__global__ void rownorm(float* __restrict__ p)
{
    int row = blockIdx.x, t = threadIdx.x;   // 128 threads
    __shared__ float red[128];
    float x = 0.f, v = 0.f;
    if (t < ROIN) { x = p[row * ROIN + t]; v = x * x; }
    red[t] = v; __syncthreads();
    for (int off = 64; off > 0; off >>= 1) { if (t < off) red[t] += red[t + off]; __syncthreads(); }
    float inv = 1.f / sqrtf(red[0]);
    if (t < ROIN) p[row * ROIN + t] = x * inv;
}

// global min/max of sim
__global__ void minmax_part(const float* __restrict__ sim, float* __restrict__ mm)
{
    int t = threadIdx.x, b = blockIdx.x;   // 512 x 256
    float mn = 1e30f, mx = -1e30f;
    for (size_t i = (size_t)b * 256 + t; i < 1048576u; i += 512u * 256u) {
        float v = sim[i]; mn = fminf(mn, v); mx = fmaxf(mx, v);
    }
    __shared__ float smn[256], smx[256];
    smn[t] = mn; smx[t] = mx; __syncthreads();
    for (int off = 128; off > 0; off >>= 1) {
        if (t < off) { smn[t] = fminf(smn[t], smn[t + off]); smx[t] = fmaxf(smx[t], smx[t + off]); }
        __syncthreads();
    }
    if (t == 0) { mm[b] = smn[0]; mm[512 + b] = smx[0]; }
}
__global__ void minmax_final(const float* __restrict__ mm, float* __restrict__ fscal)
{
    int t = threadIdx.x;   // 512 threads
    __shared__ float smn[512], smx[512];
    smn[t] = mm[t]; smx[t] = mm[512 + t]; __syncthreads();
    for (int off = 256; off > 0; off >>= 1) {
        if (t < off) { smn[t] = fminf(smn[t], smn[t + off]); smx[t] = fmaxf(smx[t], smx[t + off]); }
        __syncthreads();
    }
    if (t == 0) { fscal[0] = smn[0]; fscal[1] = smx[0]; }
}

// labels[i] = argmax(site[i,0..3]) (first max)
__global__ void labels_k(const int* __restrict__ site, int* __restrict__ labels)
{
    int i = blockIdx.x * 256 + threadIdx.x;
    if (i >= NBZ) return;
    int best = site[4 * i], bi = 0;
    #pragma unroll
    for (int k = 1; k < 4; ++k) { int v = site[4 * i + k]; if (v > best) { best = v; bi = k; } }
    labels[i] = bi;
}

__global__ void rowcnt_k(const int* __restrict__ labels, int* __restrict__ rowcnt)
{
    int i = blockIdx.x * 256 + threadIdx.x;
    if (i >= NBZ) return;
    int li = labels[i], c = 0;
    for (int j = 0; j < NBZ; ++j) c += (labels[j] == li);
    rowcnt[i] = c;
}

// exclusive scan of per-row positive counts; iscal[0]=npos, iscal[1]=m
__global__ __launch_bounds__(1024) void scan_k(const int* __restrict__ rowcnt,
                                               int* __restrict__ rowoff, int* __restrict__ iscal)
{
    __shared__ int s[1024];
    int t = threadIdx.x;
    int c = rowcnt[t];
    s[t] = c; __syncthreads();
    for (int off = 1; off < 1024; off <<= 1) {
        int v = (t >= off) ? s[t - off] : 0;
        __syncthreads();
        s[t] += v;
        __syncthreads();
    }
    rowoff[t] = s[t] - c;
    if (t == 1023) {
        int npos = s[1023];
        int nneg = 1024 * 1024 - npos;
        iscal[0] = npos;
        iscal[1] = (npos < nneg) ? npos : nneg;
    }
}

// scatter sim values to rank-paired pos/neg arrays
__global__ void pair_scatter(const int* __restrict__ labels, const int* __restrict__ rowoff,
                             const int* __restrict__ iscal, const float* __restrict__ sim,
                             float* __restrict__ posval, float* __restrict__ negval)
{
    int row = blockIdx.x, t = threadIdx.x;
    int m = iscal[1];
    int li = labels[row];
    int j0 = t * 4;
    int eq[4]; int c = 0;
    #pragma unroll
    for (int kk = 0; kk < 4; ++kk) { eq[kk] = (labels[j0 + kk] == li); c += eq[kk]; }
    __shared__ int s[256];
    s[t] = c; __syncthreads();
    for (int off = 1; off < 256; off <<= 1) {
        int v = (t >= off) ? s[t - off] : 0;
        __syncthreads();
        s[t] += v;
        __syncthreads();
    }
    int r = rowoff[row] + s[t] - c;
    size_t base = (size_t)row * 1024;
    #pragma unroll
    for (int kk = 0; kk < 4; ++kk) {
        size_t f = base + j0 + kk;
        float v = sim[f];
        if (eq[kk]) { if (r < m) posval[r] = v; r++; }
        else { long nr = (long)f - r; if (nr < m) negval[nr] = v; }
    }
}

__global__ void loss_part(const float* __restrict__ posval, const float* __restrict__ negval,
                          const int* __restrict__ iscal, float* __restrict__ lp)
{
    int m = iscal[1];
    int t = threadIdx.x, b = blockIdx.x;   // 1024 x 256
    float s = 0.f;
    for (int k = b * 256 + t; k < m; k += 1024 * 256) {
        float d = negval[k] - posval[k];
        s += fmaxf(d, 0.f) + log1pf(expf(-fabsf(d)));
    }
    __shared__ float red[256];
    red[t] = s; __syncthreads();
    for (int off = 128; off > 0; off >>= 1) { if (t < off) red[t] += red[t + off]; __syncthreads(); }
    if (t == 0) lp[b] = red[0];
}

__global__ void loss_final(const float* __restrict__ lp, const int* __restrict__ iscal,
                           float* __restrict__ outp)
{
    int t = threadIdx.x;   // 256
    double s = 0.0;
    for (int k = t; k < 1024; k += 256) s += (double)lp[k];
    __shared__ double red[256];
    red[t] = s; __syncthreads();
    for (int off = 128; off > 0; off >>= 1) { if (t < off) red[t] += red[t + off]; __syncthreads(); }
    if (t == 0) {
        int m = iscal[1]; if (m < 1) m = 1;
        outp[0] = (float)(red[0] / (double)m);
    }
}

// row-wise top-8 (ties -> lower index); per-wave shfl reduce + 4-way final
__global__ void topk8(const float* __restrict__ dist, float* __restrict__ topv, int* __restrict__ topi)
{
    int row = blockIdx.x, t = threadIdx.x;
    const int wid = t >> 6, lane = t & 63;
    __shared__ float sv[1024];
    __shared__ float wv[4];
    __shared__ int   wi[4];
    for (int j = t; j < 1024; j += 256) sv[j] = dist[(size_t)row * 1024 + j];
    __syncthreads();
    for (int k = 0; k < 8; ++k) {
        float bv = -1e30f; int bi = 1 << 20;
        for (int j = t; j < 1024; j += 256) {
            float x = sv[j];
            if (x > bv || (x == bv && j < bi)) { bv = x; bi = j; }
        }
        #pragma unroll
        for (int off = 32; off > 0; off >>= 1) {
            float ov = __shfl_down(bv, off);
            int oi = __shfl_down(bi, off);
            if (ov > bv || (ov == bv && oi < bi)) { bv = ov; bi = oi; }
        }
        if (lane == 0) { wv[wid] = bv; wi[wid] = bi; }
        __syncthreads();
        if (t == 0) {
            float fv = wv[0]; int fi = wi[0];
            #pragma unroll
            for (int q = 1; q < 4; ++q) {
                if (wv[q] > fv || (wv[q] == fv && wi[q] < fi)) { fv = wv[q]; fi = wi[q]; }
            }
            topv[row * 8 + k] = fv; topi[row * 8 + k] = fi; sv[fi] = -1e30f;
        }
        __syncthreads();
    }
}

// bn3: per-ROI-channel stats over (N=1024, L=8); writes final output
__global__ void bn3_k(const float* __restrict__ X, const float* __restrict__ g,
                      const float* __restrict__ bta, float* __restrict__ out)
{
    int c = blockIdx.x, t = threadIdx.x;   // 116 x 256
    float s = 0.f, s2 = 0.f;
    for (int k = t; k < 8192; k += 256) {
        int n = k >> 3, l = k & 7;
        float v = X[(size_t)n * 928 + c * 8 + l];
        s += v; s2 += v * v;
    }
    __shared__ float rs[256], rs2[256];
    rs[t] = s; rs2[t] = s2; __syncthreads();
    for (int off = 128; off > 0; off >>= 1) {
        if (t < off) { rs[t] += rs[t + off]; rs2[t] += rs2[t + off]; }
        __syncthreads();
    }
    __shared__ float sm, sr;
    if (t == 0) {
        float mean = rs[0] / 8192.f;
        float var = rs2[0] / 8192.f - mean * mean;
        sm = mean; sr = 1.f / sqrtf(var + EPSBN);
    }
    __syncthreads();
    float mean = sm, rstd = sr, gg = g[c], bb = bta[c];
    for (int k = t; k < 8192; k += 256) {
        int n = k >> 3, l = k & 7;
        size_t idx = (size_t)n * 928 + c * 8 + l;
        out[idx] = (X[idx] - mean) * rstd * gg + bb;
    }
}

// ---------------------------------------------------------------------------
extern "C" void kernel_launch(void* const* d_in, const int* in_sizes, int n_in,
                              void* d_out, int out_size, void* d_ws, size_t ws_size,
                              hipStream_t stream)
{
    const float* x        = (const float*)d_in[0];
    const float* pseudo   = (const float*)d_in[1];
    const int*   ages     = (const int*)d_in[2];
    const int*   genders  = (const int*)d_in[3];
    const int*   site     = (const int*)d_in[4];
    const float* fc_p_w   = (const float*)d_in[5];
    const float* fc_p_b   = (const float*)d_in[6];
    const float* proj_w1  = (const float*)d_in[7];
    const float* proj_b1  = (const float*)d_in[8];
    const float* proj_w2  = (const float*)d_in[9];
    const float* proj_b2  = (const float*)d_in[10];
    const float* gcn_w1   = (const float*)d_in[11];
    const float* gcn_b1   = (const float*)d_in[12];
    const float* gcn_w2   = (const float*)d_in[13];
    const float* gcn_b2   = (const float*)d_in[14];
    const float* gcn1_w   = (const float*)d_in[15];
    const float* gcn1_b   = (const float*)d_in[16];
    const float* gcn2_w1  = (const float*)d_in[17];
    const float* gcn2_b1  = (const float*)d_in[18];
    const float* gcn2_w2  = (const float*)d_in[19];
    const float* gcn2_b2  = (const float*)d_in[20];
    const float* bn1_g    = (const float*)d_in[21];
    const float* bn1_b    = (const float*)d_in[22];
    const float* bn2_g    = (const float*)d_in[23];
    const float* bn2_b    = (const float*)d_in[24];
    const float* bn3_g    = (const float*)d_in[25];
    const float* bn3_b    = (const float*)d_in[26];
    float* dout = (float*)d_out;

    char* w = (char*)d_ws;
    size_t off = 0;
    auto carve = [&](size_t bytes) { char* p = w + off; off = (off + bytes + 255) & ~(size_t)255; return p; };
    float* xf     = (float*)carve((size_t)NROWS * LDF * 4);   // 58.0 MB (PERMUTED cols)
    float* hA     = (float*)carve((size_t)NROWS * LDF * 4);
    float* hB     = (float*)carve((size_t)NROWS * LDF * 4);
    float* G      = (float*)carve(1048576u * 4);
    float* simb   = (float*)carve(1048576u * 4);
    float* t1     = (float*)carve((size_t)NBZ * ROIN * 4);
    float* pbuf   = (float*)carve((size_t)NBZ * ROIN * 4);
    float* sq     = (float*)carve(4096);
    float* rsq    = (float*)carve((size_t)NROWS * 4);
    int*   labels = (int*)carve(4096);
    int*   rowcnt = (int*)carve(4096);
    int*   rowoff = (int*)carve(4096);
    int*   iscal  = (int*)carve(256);
    float* fscal  = (float*)carve(256);
    float* posval = (float*)carve(524288u * 4);
    float* negval = (float*)carve(524288u * 4);
    float* lpart  = (float*)carve(4096);
    float* mmpart = (float*)carve(4096);
    float* topv   = (float*)carve(32768);
    int*   topi   = (int*)carve(32768);
    float* statp  = (float*)carve((size_t)232 * GX2 * 4);
    float* sbAp   = (float*)carve(512);
    float* tbAp   = (float*)carve(512);
    float* sbBp   = (float*)carve(512);
    float* tbBp   = (float*)carve(512);
    short* wt1_hi = (short*)carve((size_t)128 * W1LD * 2);    // 3.8 MB
    short* wt1_lo = (short*)carve((size_t)128 * W1LD * 2);
    short* wts    = (short*)carve((size_t)7 * 2 * 16384 * 2);
    // aliases into dead phases:
    float* ppart  = hA;                                 // proj1 partials (13.8 MB)
    float* gpart  = xf;                                 // Gram partials 24*36*64KB = 54 MB (xf dead after proj1)
    short* xfh    = (short*)((char*)hB + (16u << 20));  // bf16 xf 30.4 MB at hB+16MB
    short* actH1  = (short*)hA;                         // 29.7 MB (ppart dead)
    short* actH2  = (short*)hB;                         // 29.7 MB (xfh dead after wg1)
    short* actH3  = (short*)hA;                         // 29.7 MB (actH1 dead)
    float* h45    = hB;                                 // 3.8 MB (actH2 dead)

    auto wt_hi = [&](int i) { return wts + (size_t)i * 2 * 16384; };
    auto wt_lo = [&](int i) { return wts + (size_t)i * 2 * 16384 + 16384; };

    // 0. weight pretranspose + hi/lo split (PERM for permuted-A consumers)
    wt1_conv<<<(128 * W1LD) / 256, 256, 0, stream>>>(proj_w1, wt1_hi, wt1_lo);
    wt_conv<false><<<64, 256, 0, stream>>>(fc_p_w,  wt_hi(0), wt_lo(0), 116, 116);
    wt_conv<false><<<64, 256, 0, stream>>>(proj_w2, wt_hi(1), wt_lo(1), 116, 116);
    wt_conv<true ><<<64, 256, 0, stream>>>(gcn_w1,  wt_hi(2), wt_lo(2), 116, 116);
    wt_conv<true ><<<64, 256, 0, stream>>>(gcn_w2,  wt_hi(3), wt_lo(3), 116, 116);
    wt_conv<true ><<<64, 256, 0, stream>>>(gcn1_w,  wt_hi(4), wt_lo(4), 116, 116);
    wt_conv<true ><<<64, 256, 0, stream>>>(gcn2_w1, wt_hi(5), wt_lo(5), 116, 64);
    wt_conv<false><<<64, 256, 0, stream>>>(gcn2_w2, wt_hi(6), wt_lo(6), 64, 8);

    // 1. xf(permuted fp32) = x + leaky(pseudo @ fc_p_w + b); bf16 xfh + row sumsq
    mfma_gemm_w<4, 1, false><<<GX2, 512, 0, stream>>>(pseudo, wt_hi(0), wt_lo(0), fc_p_b, x, xf,
                                                      xfh, rsq, ROIN, LDF);
    sq_reduce<<<4, 256, 0, stream>>>(rsq, sq);

    // 2. proj head (wt1 K-permuted to match permuted xf)
    mfma_proj1<<<dim3(16, 1, PZ), 256, 0, stream>>>(xf, wt1_hi, wt1_lo, ppart);
    proj_reduce<<<(NBZ * ROIN + 255) / 256, 256, 0, stream>>>(ppart, proj_b1, t1);
    mfma_gemm_w<1, 0, false><<<8, 512, 0, stream>>>(t1, wt_hi(1), wt_lo(1), proj_b2, nullptr, pbuf,
                                                    nullptr, nullptr, ROIN, ROIN);
    rownorm<<<NBZ, 128, 0, stream>>>(pbuf);

    // 3. sim = (pn @ pn^T) / TEMP
    gemm_nt_sym<<<dim3(16, 16, 1), 256, 0, stream>>>(pbuf, simb, NBZ, ROIN, 1.f / 0.07f);

    // 4. contrastive loss
    labels_k<<<4, 256, 0, stream>>>(site, labels);
    rowcnt_k<<<4, 256, 0, stream>>>(labels, rowcnt);
    scan_k<<<1, 1024, 0, stream>>>(rowcnt, rowoff, iscal);
    pair_scatter<<<NBZ, 256, 0, stream>>>(labels, rowoff, iscal, simb, posval, negval);
    loss_part<<<1024, 256, 0, stream>>>(posval, negval, iscal, lpart);
    loss_final<<<1, 256, 0, stream>>>(lpart, iscal, dout + (size_t)NBZ * ROIN * 8);

    // 5. sim min/max, Gram (XCD-affine, 24-way split-K into dead xf), dist, top-k
    minmax_part<<<512, 256, 0, stream>>>(simb, mmpart);
    minmax_final<<<1, 512, 0, stream>>>(mmpart, fscal);
    gram_mfma<<<NTRI * GRAMZ, 256, 0, stream>>>(xfh, gpart);
    gram_reduce_dist<<<dim3(NTRI, 16), 256, 0, stream>>>(gpart, simb, sq, ages, genders, fscal, G);
    topk8<<<NBZ, 256, 0, stream>>>(G, topv, topi);

    // 6. GCN stack on bf16-permuted activations (W-lo dropped)
    mfma_gemm_wg_h<0, false><<<GX2, 512, 0, stream>>>(topv, topi, xfh, nullptr, nullptr,
                                                      wt_hi(2), gcn_b1, actH1, nullptr);
    mfma_gemm_bA<<<GX2, 512, 0, stream>>>(actH1, wt_hi(3), gcn_b2, actH2, statp);
    bn_final_st_p<<<128, 256, 0, stream>>>(statp, bn1_g, bn1_b, sbAp, tbAp, GX2);

    mfma_gemm_wg_h<2, true><<<GX2, 512, 0, stream>>>(topv, topi, actH2, sbAp, tbAp,
                                                     wt_hi(4), gcn1_b, actH3, statp);
    bn_final_st_p<<<128, 256, 0, stream>>>(statp, bn2_g, bn2_b, sbBp, tbBp, GX2);

    mfma_gemm45_wg_h<<<GX45, 256, 0, stream>>>(topv, topi, actH3, sbBp, tbBp,
                                               wt_hi(5), gcn2_b1,
                                               wt_hi(6), gcn2_b2, h45);

    // 7. bn3 -> d_out
    bn3_k<<<116, 256, 0, stream>>>(h45, bn3_g, bn3_b, dout);
}

// Round 17
// 588.939 us; speedup vs baseline: 1.0181x; 1.0181x over previous
//
#include <hip/hip_runtime.h>
#include <math.h>

#define ROIN 116
#define NBZ 1024
#define LDF 128            // padded ROI-row length (floats / bf16)
#define SROW (ROIN*LDF)    // 14848: padded per-sample flat row
#define NROWS (NBZ*ROIN)   // 118784
#define ALPHA 0.1f
#define ACOEF 0.9f
#define BETAC 2
#define EPSBN 1e-5f
#define PZ 29              // proj1 split-K chunks (29*512 = 14848)
#define PCH 512
#define W1LD SROW
#define GX2 928            // NROWS/128 (512-thread GEMM blocks)
#define GX45 1856          // NROWS/64 (gemm45 blocks)
#define GRAMZ 16
#define GRAMKS 928         // 16*928 = 14848
#define NTRI 36            // upper-tri 128x128 tiles of 8x8 grid

typedef __attribute__((ext_vector_type(8))) short bf16x8;
typedef __attribute__((ext_vector_type(4))) float f32x4;

__device__ __forceinline__ float leakyf(float v){ return v >= 0.f ? v : 0.2f*v; }

__device__ __forceinline__ short f2bf(float f){
    unsigned u = __builtin_bit_cast(unsigned, f);
    unsigned r = u + 0x7fffu + ((u >> 16) & 1u);   // RNE
    return (short)(r >> 16);
}
__device__ __forceinline__ float bf2f(short h){
    unsigned u = ((unsigned)(unsigned short)h) << 16;
    return __builtin_bit_cast(float, u);
}

// Column permutation used by all bf16-permuted activation emits:
// logical col c -> stored col (c&15)*8 + (c>>4)   (bijection on [0,128))

// ---------------------------------------------------------------------------
// Weight pretranspose + bf16 hi/lo split. Small weights -> WT[128][128].
// PERM: permute K-dim to match permuted bf16 activations.
// ---------------------------------------------------------------------------
template<bool PERM>
__global__ void wt_conv(const float* __restrict__ W, short* __restrict__ hi,
                        short* __restrict__ lo, int K, int N)
{
    int idx = blockIdx.x * 256 + threadIdx.x;   // 16384
    int n = idx >> 7, kp = idx & 127;
    int k = PERM ? ((kp & 7) * 16 + (kp >> 3)) : kp;
    float v = (n < N && k < K) ? W[(size_t)k * N + n] : 0.f;
    short h = f2bf(v);
    hi[idx] = h;
    lo[idx] = f2bf(v - bf2f(h));
}

// proj_w1 [13456,116] -> WT1[128][14848] hi/lo (padded-K indexing: k'=r*128+d)
__global__ void wt1_conv(const float* __restrict__ W, short* __restrict__ hi,
                         short* __restrict__ lo)
{
    int idx = blockIdx.x * 256 + threadIdx.x;   // 128*14848
    int n = idx / W1LD, k = idx - n * W1LD;
    int r = k >> 7, d = k & 127;
    float v = (n < ROIN && d < ROIN) ? W[(size_t)(r * ROIN + d) * ROIN + n] : 0.f;
    short h = f2bf(v);
    hi[idx] = h;
    lo[idx] = f2bf(v - bf2f(h));
}

// ---------------------------------------------------------------------------
// bf16x2 MFMA GEMM, 512 threads, 128 rows/block, LDS-staged weights.
// EPI: 1 bias, 3 leaky(bias), 4 X + leaky(bias)
// XTRA: 0 none; 1 bf16 C (permuted cols: col'=rl*8+nf) + row sumsq
// ---------------------------------------------------------------------------
template<int EPI, int XTRA, bool PADK>
__global__ __launch_bounds__(512) void mfma_gemm_w(
    const float* __restrict__ A, const short* __restrict__ wt_hi,
    const short* __restrict__ wt_lo, const float* __restrict__ bias,
    const float* __restrict__ X, float* __restrict__ C,
    short* __restrict__ bfout, float* __restrict__ rsq,
    int LDA, int LDC)
{
    __shared__ short whi[128][136];
    __shared__ short wlo[128][136];
    const int tid = threadIdx.x;
    {
        int r = tid >> 2, q = tid & 3;
        const short* sh = wt_hi + r * 128 + q * 32;
        const short* sl = wt_lo + r * 128 + q * 32;
        #pragma unroll
        for (int i = 0; i < 4; ++i) {
            *(bf16x8*)(&whi[r][q * 32 + i * 8]) = *(const bf16x8*)(sh + i * 8);
            *(bf16x8*)(&wlo[r][q * 32 + i * 8]) = *(const bf16x8*)(sl + i * 8);
        }
    }
    __syncthreads();
    const int wave = tid >> 6, lane = tid & 63;
    const int m0 = blockIdx.x * 128 + wave * 16;
    const int rl = lane & 15, g = lane >> 4;
    const float* Arow = A + (size_t)(m0 + rl) * LDA;
    float av[4][8];
    #pragma unroll
    for (int s = 0; s < 4; ++s) {
        const int kk = s * 32 + g * 8;
        if (PADK || kk + 8 <= ROIN) {
            float4 p = *(const float4*)(Arow + kk);
            float4 q = *(const float4*)(Arow + kk + 4);
            av[s][0]=p.x; av[s][1]=p.y; av[s][2]=p.z; av[s][3]=p.w;
            av[s][4]=q.x; av[s][5]=q.y; av[s][6]=q.z; av[s][7]=q.w;
        } else if (kk + 4 <= ROIN) {
            float4 p = *(const float4*)(Arow + kk);
            av[s][0]=p.x; av[s][1]=p.y; av[s][2]=p.z; av[s][3]=p.w;
            av[s][4]=0.f; av[s][5]=0.f; av[s][6]=0.f; av[s][7]=0.f;
        } else {
            #pragma unroll
            for (int j = 0; j < 8; ++j) av[s][j] = 0.f;
        }
    }
    f32x4 acc[8];
    #pragma unroll
    for (int nf = 0; nf < 8; ++nf) acc[nf] = (f32x4){0.f,0.f,0.f,0.f};
    #pragma unroll
    for (int s = 0; s < 4; ++s) {
        const int kk = s * 32 + g * 8;
        bf16x8 ah, al;
        #pragma unroll
        for (int j = 0; j < 8; ++j) {
            short h = f2bf(av[s][j]); ah[j] = h;
            al[j] = f2bf(av[s][j] - bf2f(h));
        }
        #pragma unroll
        for (int nf = 0; nf < 8; ++nf) {
            const bf16x8 bh = *(const bf16x8*)(&whi[nf * 16 + rl][kk]);
            const bf16x8 bl = *(const bf16x8*)(&wlo[nf * 16 + rl][kk]);
            acc[nf] = __builtin_amdgcn_mfma_f32_16x16x32_bf16(ah, bh, acc[nf], 0, 0, 0);
            acc[nf] = __builtin_amdgcn_mfma_f32_16x16x32_bf16(al, bh, acc[nf], 0, 0, 0);
            acc[nf] = __builtin_amdgcn_mfma_f32_16x16x32_bf16(ah, bl, acc[nf], 0, 0, 0);
        }
    }
    const int cm = g * 4;
    float rq[4] = {0.f, 0.f, 0.f, 0.f};
    bf16x8 bfv[4];
    #pragma unroll
    for (int nf = 0; nf < 8; ++nf) {
        int n = nf * 16 + rl;
        float bb = (n < ROIN) ? bias[n] : 0.f;
        #pragma unroll
        for (int j = 0; j < 4; ++j) {
            int m = m0 + cm + j;
            size_t idx = (size_t)m * LDC + n;
            float v = 0.f;
            if (n < ROIN) {
                v = acc[nf][j] + bb;
                if (EPI == 3) v = leakyf(v);
                else if (EPI == 4) v = X[(size_t)m * LDA + n] + leakyf(v);
            }
            if (n < LDC) C[idx] = v;
            if (XTRA == 1) { bfv[j][nf] = f2bf(v); rq[j] += v * v; }
        }
    }
    if (XTRA == 1) {
        #pragma unroll
        for (int j = 0; j < 4; ++j)
            *(bf16x8*)(&bfout[(size_t)(m0 + cm + j) * LDF + rl * 8]) = bfv[j];
        #pragma unroll
        for (int j = 0; j < 4; ++j) {
            rq[j] += __shfl_xor(rq[j], 1);
            rq[j] += __shfl_xor(rq[j], 2);
            rq[j] += __shfl_xor(rq[j], 4);
            rq[j] += __shfl_xor(rq[j], 8);
        }
        if (rl == 0) {
            #pragma unroll
            for (int j = 0; j < 4; ++j) rsq[m0 + cm + j] = rq[j];
        }
    }
}

// ---------------------------------------------------------------------------
// Gather-fused GEMM on bf16-permuted activations (pipelined gather).
// feat: bf16 permuted rows [NROWS][128]; weights K-permuted; sbP/tbP permuted
// (zeros at pad slots). Emits bf16-permuted out (+BN stats if XTRA==2).
// Epilogue: leaky(acc + bias).
// ---------------------------------------------------------------------------
template<int XTRA, bool FOLD>
__global__ __launch_bounds__(512, 4) void mfma_gemm_wg_h(
    const float* __restrict__ vals, const int* __restrict__ idxs,
    const short* __restrict__ feat, const float* __restrict__ sbP,
    const float* __restrict__ tbP,
    const short* __restrict__ wt_hi, const short* __restrict__ wt_lo,
    const float* __restrict__ bias, short* __restrict__ outH,
    float* __restrict__ statp)
{
    __shared__ short whi[128][136];
    __shared__ short wlo[128][136];
    __shared__ float st[(XTRA == 2) ? 8 : 1][2][128];
    const int tid = threadIdx.x;
    {
        int r = tid >> 2, q = tid & 3;
        const short* sh = wt_hi + r * 128 + q * 32;
        const short* sl = wt_lo + r * 128 + q * 32;
        #pragma unroll
        for (int i = 0; i < 4; ++i) {
            *(bf16x8*)(&whi[r][q * 32 + i * 8]) = *(const bf16x8*)(sh + i * 8);
            *(bf16x8*)(&wlo[r][q * 32 + i * 8]) = *(const bf16x8*)(sl + i * 8);
        }
    }
    __syncthreads();
    const int wave = tid >> 6, lane = tid & 63;
    const int m0 = blockIdx.x * 128 + wave * 16;
    const int rl = lane & 15, g = lane >> 4;
    const int m = m0 + rl;
    const unsigned bz = (unsigned)m / 116u;
    const int r = m - (int)bz * 116;
    float vv[8]; const short* fp[8];
    #pragma unroll
    for (int k = 0; k < 8; ++k) {
        vv[k] = vals[bz * 8 + k];
        int ixk = idxs[bz * 8 + k];
        fp[k] = feat + ((size_t)ixk * 116 + r) * 128;
    }
    float wsum = 0.f;
    if (FOLD) {
        #pragma unroll
        for (int k = 0; k < 8; ++k) wsum += vv[k];
    }
    f32x4 acc[8];
    #pragma unroll
    for (int nf = 0; nf < 8; ++nf) acc[nf] = (f32x4){0.f,0.f,0.f,0.f};
    bf16x8 xb[8], xn[8];
    #pragma unroll
    for (int k = 0; k < 8; ++k) xb[k] = *(const bf16x8*)(fp[k] + g * 8);
    #pragma unroll
    for (int s = 0; s < 4; ++s) {
        const int kk = s * 32 + g * 8;
        if (s < 3) {
            #pragma unroll
            for (int k = 0; k < 8; ++k) xn[k] = *(const bf16x8*)(fp[k] + kk + 32);
        }
        float av[8] = {0.f,0.f,0.f,0.f,0.f,0.f,0.f,0.f};
        #pragma unroll
        for (int k = 0; k < 8; ++k) {
            const float vk = vv[k];
            #pragma unroll
            for (int j = 0; j < 8; ++j) av[j] = fmaf(vk, bf2f(xb[k][j]), av[j]);
        }
        if (FOLD) {
            #pragma unroll
            for (int j = 0; j < 8; ++j)
                av[j] = sbP[kk + j] * av[j] + wsum * tbP[kk + j];   // pads: 0*0+w*0=0
        }
        bf16x8 ah, al;
        #pragma unroll
        for (int j = 0; j < 8; ++j) {
            short h = f2bf(av[j]); ah[j] = h;
            al[j] = f2bf(av[j] - bf2f(h));
        }
        __builtin_amdgcn_s_setprio(1);
        #pragma unroll
        for (int nf = 0; nf < 8; ++nf) {
            const bf16x8 bh = *(const bf16x8*)(&whi[nf * 16 + rl][kk]);
            const bf16x8 bl = *(const bf16x8*)(&wlo[nf * 16 + rl][kk]);
            acc[nf] = __builtin_amdgcn_mfma_f32_16x16x32_bf16(ah, bh, acc[nf], 0, 0, 0);
            acc[nf] = __builtin_amdgcn_mfma_f32_16x16x32_bf16(al, bh, acc[nf], 0, 0, 0);
            acc[nf] = __builtin_amdgcn_mfma_f32_16x16x32_bf16(ah, bl, acc[nf], 0, 0, 0);
        }
        __builtin_amdgcn_s_setprio(0);
        #pragma unroll
        for (int k = 0; k < 8; ++k) xb[k] = xn[k];
    }
    const int cm = g * 4;
    bf16x8 bfv[4];
    #pragma unroll
    for (int nf = 0; nf < 8; ++nf) {
        int n = nf * 16 + rl;
        float c1 = 0.f, c2 = 0.f;
        float bb = (n < ROIN) ? bias[n] : 0.f;
        #pragma unroll
        for (int j = 0; j < 4; ++j) {
            float v = 0.f;
            if (n < ROIN) v = leakyf(acc[nf][j] + bb);
            bfv[j][nf] = f2bf(v);
            if (XTRA == 2) { c1 += v; c2 += v * v; }
        }
        if (XTRA == 2) {
            c1 += __shfl_xor(c1, 16); c1 += __shfl_xor(c1, 32);
            c2 += __shfl_xor(c2, 16); c2 += __shfl_xor(c2, 32);
            if (lane < 16) { st[wave][0][n & 127] = c1; st[wave][1][n & 127] = c2; }
        }
    }
    #pragma unroll
    for (int j = 0; j < 4; ++j)
        *(bf16x8*)(&outH[(size_t)(m0 + cm + j) * LDF + rl * 8]) = bfv[j];
    if (XTRA == 2) {
        __syncthreads();
        if (tid < 232) {
            int sel = tid < 116 ? 0 : 1;
            int c = sel ? tid - 116 : tid;
            float s = 0.f;
            #pragma unroll
            for (int wv = 0; wv < 8; ++wv) s += st[wv][sel][c];
            statp[(size_t)(sel * 116 + c) * GX2 + blockIdx.x] = s;
        }
    }
}

// ---------------------------------------------------------------------------
// bf16-A GEMM (gcn_w2): A = bf16 permuted rows; weights K-permuted.
// C = A@W + bias (no leaky). Emits bf16-permuted out + BN1 stats.
// ---------------------------------------------------------------------------
__global__ __launch_bounds__(512) void mfma_gemm_bA(
    const short* __restrict__ A,
    const short* __restrict__ wt_hi, const short* __restrict__ wt_lo,
    const float* __restrict__ bias, short* __restrict__ outH,
    float* __restrict__ statp)
{
    __shared__ short whi[128][136];
    __shared__ short wlo[128][136];
    __shared__ float st[8][2][128];
    const int tid = threadIdx.x;
    {
        int r = tid >> 2, q = tid & 3;
        const short* sh = wt_hi + r * 128 + q * 32;
        const short* sl = wt_lo + r * 128 + q * 32;
        #pragma unroll
        for (int i = 0; i < 4; ++i) {
            *(bf16x8*)(&whi[r][q * 32 + i * 8]) = *(const bf16x8*)(sh + i * 8);
            *(bf16x8*)(&wlo[r][q * 32 + i * 8]) = *(const bf16x8*)(sl + i * 8);
        }
    }
    __syncthreads();
    const int wave = tid >> 6, lane = tid & 63;
    const int m0 = blockIdx.x * 128 + wave * 16;
    const int rl = lane & 15, g = lane >> 4;
    const short* Arow = A + (size_t)(m0 + rl) * LDF;
    bf16x8 av[4];
    #pragma unroll
    for (int s = 0; s < 4; ++s) av[s] = *(const bf16x8*)(Arow + s * 32 + g * 8);
    f32x4 acc[8];
    #pragma unroll
    for (int nf = 0; nf < 8; ++nf) acc[nf] = (f32x4){0.f,0.f,0.f,0.f};
    #pragma unroll
    for (int s = 0; s < 4; ++s) {
        const int kk = s * 32 + g * 8;
        const bf16x8 ah = av[s];
        #pragma unroll
        for (int nf = 0; nf < 8; ++nf) {
            const bf16x8 bh = *(const bf16x8*)(&whi[nf * 16 + rl][kk]);
            const bf16x8 bl = *(const bf16x8*)(&wlo[nf * 16 + rl][kk]);
            acc[nf] = __builtin_amdgcn_mfma_f32_16x16x32_bf16(ah, bh, acc[nf], 0, 0, 0);
            acc[nf] = __builtin_amdgcn_mfma_f32_16x16x32_bf16(ah, bl, acc[nf], 0, 0, 0);
        }
    }
    const int cm = g * 4;
    bf16x8 bfv[4];
    #pragma unroll
    for (int nf = 0; nf < 8; ++nf) {
        int n = nf * 16 + rl;
        float c1 = 0.f, c2 = 0.f;
        float bb = (n < ROIN) ? bias[n] : 0.f;
        #pragma unroll
        for (int j = 0; j < 4; ++j) {
            float v = 0.f;
            if (n < ROIN) v = acc[nf][j] + bb;
            bfv[j][nf] = f2bf(v);
            c1 += v; c2 += v * v;
        }
        c1 += __shfl_xor(c1, 16); c1 += __shfl_xor(c1, 32);
        c2 += __shfl_xor(c2, 16); c2 += __shfl_xor(c2, 32);
        if (lane < 16) { st[wave][0][n & 127] = c1; st[wave][1][n & 127] = c2; }
    }
    #pragma unroll
    for (int j = 0; j < 4; ++j)
        *(bf16x8*)(&outH[(size_t)(m0 + cm + j) * LDF + rl * 8]) = bfv[j];
    __syncthreads();
    if (tid < 232) {
        int sel = tid < 116 ? 0 : 1;
        int c = sel ? tid - 116 : tid;
        float s = 0.f;
        #pragma unroll
        for (int wv = 0; wv < 8; ++wv) s += st[wv][sel][c];
        statp[(size_t)(sel * 116 + c) * GX2 + blockIdx.x] = s;
    }
}

// ---------------------------------------------------------------------------
// Gather-fused pair on bf16-permuted activations:
// C[NROWS][8] = leaky(leaky(BN-gath @ W5(perm) + b5) @ W6 + b6)
// ---------------------------------------------------------------------------
__global__ __launch_bounds__(256) void mfma_gemm45_wg_h(
    const float* __restrict__ vals, const int* __restrict__ idxs,
    const short* __restrict__ feat, const float* __restrict__ sbP,
    const float* __restrict__ tbP,
    const short* __restrict__ w5h, const short* __restrict__ w5l,
    const float* __restrict__ b5,
    const short* __restrict__ w6h, const short* __restrict__ w6l,
    const float* __restrict__ b6,
    float* __restrict__ C)
{
    __shared__ short s5h[64][136], s5l[64][136];
    __shared__ short s6h[16][136], s6l[16][136];
    __shared__ float c1s[4][16][76];
    const int tid = threadIdx.x;
    {
        int r = tid >> 2, q = tid & 3;
        const short* sh = w5h + r * 128 + q * 32;
        const short* sl = w5l + r * 128 + q * 32;
        #pragma unroll
        for (int i = 0; i < 4; ++i) {
            *(bf16x8*)(&s5h[r][q * 32 + i * 8]) = *(const bf16x8*)(sh + i * 8);
            *(bf16x8*)(&s5l[r][q * 32 + i * 8]) = *(const bf16x8*)(sl + i * 8);
        }
        if (tid < 64) {
            int r6 = tid >> 2, q6 = tid & 3;
            const short* sh6 = w6h + r6 * 128 + q6 * 32;
            const short* sl6 = w6l + r6 * 128 + q6 * 32;
            #pragma unroll
            for (int i = 0; i < 4; ++i) {
                *(bf16x8*)(&s6h[r6][q6 * 32 + i * 8]) = *(const bf16x8*)(sh6 + i * 8);
                *(bf16x8*)(&s6l[r6][q6 * 32 + i * 8]) = *(const bf16x8*)(sl6 + i * 8);
            }
        }
    }
    __syncthreads();
    const int wave = tid >> 6, lane = tid & 63;
    const int m0 = blockIdx.x * 64 + wave * 16;
    const int rl = lane & 15, g = lane >> 4;
    const int m = m0 + rl;
    const unsigned bz = (unsigned)m / 116u;
    const int r = m - (int)bz * 116;
    float vv[8]; const short* fp[8];
    #pragma unroll
    for (int k = 0; k < 8; ++k) {
        vv[k] = vals[bz * 8 + k];
        int ixk = idxs[bz * 8 + k];
        fp[k] = feat + ((size_t)ixk * 116 + r) * 128;
    }
    float wsum = 0.f;
    #pragma unroll
    for (int k = 0; k < 8; ++k) wsum += vv[k];
    f32x4 acc[4];
    #pragma unroll
    for (int nf = 0; nf < 4; ++nf) acc[nf] = (f32x4){0.f,0.f,0.f,0.f};
    bf16x8 xb[8], xn[8];
    #pragma unroll
    for (int k = 0; k < 8; ++k) xb[k] = *(const bf16x8*)(fp[k] + g * 8);
    #pragma unroll
    for (int s = 0; s < 4; ++s) {
        const int kk = s * 32 + g * 8;
        if (s < 3) {
            #pragma unroll
            for (int k = 0; k < 8; ++k) xn[k] = *(const bf16x8*)(fp[k] + kk + 32);
        }
        float av[8] = {0.f,0.f,0.f,0.f,0.f,0.f,0.f,0.f};
        #pragma unroll
        for (int k = 0; k < 8; ++k) {
            const float vk = vv[k];
            #pragma unroll
            for (int j = 0; j < 8; ++j) av[j] = fmaf(vk, bf2f(xb[k][j]), av[j]);
        }
        #pragma unroll
        for (int j = 0; j < 8; ++j)
            av[j] = sbP[kk + j] * av[j] + wsum * tbP[kk + j];
        bf16x8 ah, al;
        #pragma unroll
        for (int j = 0; j < 8; ++j) {
            short h = f2bf(av[j]); ah[j] = h;
            al[j] = f2bf(av[j] - bf2f(h));
        }
        __builtin_amdgcn_s_setprio(1);
        #pragma unroll
        for (int nf = 0; nf < 4; ++nf) {
            const bf16x8 bh = *(const bf16x8*)(&s5h[nf * 16 + rl][kk]);
            const bf16x8 bl = *(const bf16x8*)(&s5l[nf * 16 + rl][kk]);
            acc[nf] = __builtin_amdgcn_mfma_f32_16x16x32_bf16(ah, bh, acc[nf], 0, 0, 0);
            acc[nf] = __builtin_amdgcn_mfma_f32_16x16x32_bf16(al, bh, acc[nf], 0, 0, 0);
            acc[nf] = __builtin_amdgcn_mfma_f32_16x16x32_bf16(ah, bl, acc[nf], 0, 0, 0);
        }
        __builtin_amdgcn_s_setprio(0);
        #pragma unroll
        for (int k = 0; k < 8; ++k) xb[k] = xn[k];
    }
    const int cm = g * 4;
    #pragma unroll
    for (int nf = 0; nf < 4; ++nf) {
        int n = nf * 16 + rl;   // < 64
        float bb = b5[n];
        #pragma unroll
        for (int j = 0; j < 4; ++j)
            c1s[wave][cm + j][n] = leakyf(acc[nf][j] + bb);
    }
    // phase 2: K=64, N=8 (wave-local LDS; unpermuted)
    f32x4 acc2 = {0.f,0.f,0.f,0.f};
    #pragma unroll
    for (int s = 0; s < 2; ++s) {
        const int kk = s * 32 + g * 8;
        float4 p = *(const float4*)(&c1s[wave][rl][kk]);
        float4 q = *(const float4*)(&c1s[wave][rl][kk + 4]);
        float a2[8] = {p.x, p.y, p.z, p.w, q.x, q.y, q.z, q.w};
        bf16x8 ah, al;
        #pragma unroll
        for (int j = 0; j < 8; ++j) {
            short h = f2bf(a2[j]); ah[j] = h;
            al[j] = f2bf(a2[j] - bf2f(h));
        }
        const bf16x8 bh = *(const bf16x8*)(&s6h[rl][kk]);
        const bf16x8 bl = *(const bf16x8*)(&s6l[rl][kk]);
        acc2 = __builtin_amdgcn_mfma_f32_16x16x32_bf16(ah, bh, acc2, 0, 0, 0);
        acc2 = __builtin_amdgcn_mfma_f32_16x16x32_bf16(al, bh, acc2, 0, 0, 0);
        acc2 = __builtin_amdgcn_mfma_f32_16x16x32_bf16(ah, bl, acc2, 0, 0, 0);
    }
    if (rl < 8) {
        float bb = b6[rl];
        #pragma unroll
        for (int j = 0; j < 4; ++j) {
            float v = leakyf(acc2[j] + bb);
            C[(size_t)(m0 + cm + j) * 8 + rl] = v;
        }
    }
}

// BN finalize (permuted out): sbP[P(c)] = rstd*g, tbP[P(c)] = b - mean*rstd*g
// 128 blocks; c>=116 writes zeros (pad slots).
__global__ void bn_final_st_p(const float* __restrict__ statp, const float* __restrict__ g,
                              const float* __restrict__ bta, float* __restrict__ sbP,
                              float* __restrict__ tbP, int cnt)
{
    int c = blockIdx.x, tid = threadIdx.x;   // 128 x 256
    int pc = (c & 15) * 8 + (c >> 4);
    if (c >= ROIN) { if (tid == 0) { sbP[pc] = 0.f; tbP[pc] = 0.f; } return; }
    float a1 = 0.f, a2 = 0.f;
    for (int i = tid; i < cnt; i += 256) {
        a1 += statp[(size_t)c * cnt + i];
        a2 += statp[(size_t)(116 + c) * cnt + i];
    }
    __shared__ float r1[256], r2[256];
    r1[tid] = a1; r2[tid] = a2; __syncthreads();
    for (int off = 128; off > 0; off >>= 1) {
        if (tid < off) { r1[tid] += r1[tid + off]; r2[tid] += r2[tid + off]; }
        __syncthreads();
    }
    if (tid == 0) {
        float mean = r1[0] / (float)NROWS;
        float var = r2[0] / (float)NROWS - mean * mean;
        float rstd = 1.f / sqrtf(var + EPSBN);
        float s = rstd * g[c];
        sbP[pc] = s;
        tbP[pc] = bta[c] - mean * s;
    }
}

// sq[bz] = sum of 116 per-M-row sumsq partials
__global__ void sq_reduce(const float* __restrict__ rsq, float* __restrict__ sq)
{
    int i = blockIdx.x * 256 + threadIdx.x;
    if (i >= NBZ) return;
    const float* p = rsq + (size_t)i * ROIN;
    float s = 0.f;
    #pragma unroll 4
    for (int r = 0; r < ROIN; ++r) s += p[r];
    sq[i] = s;
}

// ---------------------------------------------------------------------------
// proj1 via bf16x2 MFMA, split-K over padded xf [1024][14848]
// ---------------------------------------------------------------------------
__global__ __launch_bounds__(256) void mfma_proj1(
    const float* __restrict__ A, const short* __restrict__ wt_hi,
    const short* __restrict__ wt_lo, float* __restrict__ part)
{
    const int wave = threadIdx.x >> 6, lane = threadIdx.x & 63;
    const int m0 = blockIdx.x * 64 + wave * 16;
    const int rl = lane & 15, g = lane >> 4;
    const int kbase = blockIdx.z * PCH;
    const float* Arow = A + (size_t)(m0 + rl) * SROW;
    f32x4 acc[8];
    #pragma unroll
    for (int nf = 0; nf < 8; ++nf) acc[nf] = (f32x4){0.f,0.f,0.f,0.f};
    for (int s = 0; s < 16; ++s) {
        const int kk = kbase + s * 32 + g * 8;
        float4 p = *(const float4*)(Arow + kk);
        float4 q = *(const float4*)(Arow + kk + 4);
        float av[8] = {p.x, p.y, p.z, p.w, q.x, q.y, q.z, q.w};
        bf16x8 ah, al;
        #pragma unroll
        for (int j = 0; j < 8; ++j) {
            short h = f2bf(av[j]); ah[j] = h;
            al[j] = f2bf(av[j] - bf2f(h));
        }
        #pragma unroll
        for (int nf = 0; nf < 8; ++nf) {
            size_t boff = (size_t)(nf * 16 + rl) * W1LD + kk;
            bf16x8 bh = *(const bf16x8*)(wt_hi + boff);
            bf16x8 bl = *(const bf16x8*)(wt_lo + boff);
            acc[nf] = __builtin_amdgcn_mfma_f32_16x16x32_bf16(ah, bh, acc[nf], 0, 0, 0);
            acc[nf] = __builtin_amdgcn_mfma_f32_16x16x32_bf16(al, bh, acc[nf], 0, 0, 0);
            acc[nf] = __builtin_amdgcn_mfma_f32_16x16x32_bf16(ah, bl, acc[nf], 0, 0, 0);
        }
    }
    float* Cb = part + (size_t)blockIdx.z * NBZ * ROIN;
    const int cm = g * 4;
    #pragma unroll
    for (int nf = 0; nf < 8; ++nf) {
        int n = nf * 16 + rl;
        if (n < ROIN) {
            #pragma unroll
            for (int j = 0; j < 4; ++j)
                Cb[(size_t)(m0 + cm + j) * ROIN + n] = acc[nf][j];
        }
    }
}

// split-K reduce for proj1 (+bias +relu)
__global__ void proj_reduce(const float* __restrict__ ppart,
                            const float* __restrict__ bias, float* __restrict__ t1)
{
    int e = blockIdx.x * 256 + threadIdx.x;
    if (e >= NBZ * ROIN) return;
    int n = e % ROIN;
    float s = 0.f;
    for (int z = 0; z < PZ; ++z) s += ppart[(size_t)z * NBZ * ROIN + e];
    t1[e] = fmaxf(s + bias[n], 0.f);
}

// ---------------------------------------------------------------------------
// fp32 GEMM NT (sim = pn @ pn^T, K=116), symmetric mirror write
// ---------------------------------------------------------------------------
__global__ __launch_bounds__(256) void gemm_nt_sym(
    const float* __restrict__ A, float* __restrict__ C, int M, int K, float scale)
{
    if ((int)blockIdx.y < (int)blockIdx.x) return;
    __shared__ float As[16][65];
    __shared__ float Bs[16][65];
    const int tid = threadIdx.x;
    const int m0 = blockIdx.x * 64;
    const int n0 = blockIdx.y * 64;
    const int tm4 = (tid >> 4) * 4;
    const int tn4 = (tid & 15) * 4;
    const int rA  = tid >> 2;
    const int kbA = (tid & 3) * 4;
    float acc[4][4] = {};
    for (int kt = 0; kt < K; kt += 16) {
        int kg = kt + kbA;
        if (kg + 4 <= K) {
            float4 va = *(const float4*)(A + (size_t)(m0 + rA) * K + kg);
            As[kbA + 0][rA] = va.x; As[kbA + 1][rA] = va.y;
            As[kbA + 2][rA] = va.z; As[kbA + 3][rA] = va.w;
            float4 vb = *(const float4*)(A + (size_t)(n0 + rA) * K + kg);
            Bs[kbA + 0][rA] = vb.x; Bs[kbA + 1][rA] = vb.y;
            Bs[kbA + 2][rA] = vb.z; Bs[kbA + 3][rA] = vb.w;
        } else {
            #pragma unroll
            for (int kk = 0; kk < 4; ++kk) {
                int kgg = kg + kk;
                As[kbA + kk][rA] = (kgg < K) ? A[(size_t)(m0 + rA) * K + kgg] : 0.f;
                Bs[kbA + kk][rA] = (kgg < K) ? A[(size_t)(n0 + rA) * K + kgg] : 0.f;
            }
        }
        __syncthreads();
        #pragma unroll
        for (int k = 0; k < 16; ++k) {
            float a[4], b[4];
            #pragma unroll
            for (int i = 0; i < 4; ++i) a[i] = As[k][tm4 + i];
            #pragma unroll
            for (int j = 0; j < 4; ++j) b[j] = Bs[k][tn4 + j];
            #pragma unroll
            for (int i = 0; i < 4; ++i)
                #pragma unroll
                for (int j = 0; j < 4; ++j)
                    acc[i][j] = fmaf(a[i], b[j], acc[i][j]);
        }
        __syncthreads();
    }
    #pragma unroll
    for (int i = 0; i < 4; ++i) {
        int m = m0 + tm4 + i;
        #pragma unroll
        for (int j = 0; j < 4; ++j) {
            int n = n0 + tn4 + j;
            float v = acc[i][j] * scale;
            C[(size_t)m * M + n] = v;
            C[(size_t)n * M + m] = v;
        }
    }
}

// ---------------------------------------------------------------------------
// Gram via bf16 MFMA over padded/permuted xfh. 1D grid 576 = 36 tri x 16 z,
// XCD-affine: wg = (id&7)*72 + (id>>3).
// ---------------------------------------------------------------------------
__global__ __launch_bounds__(256) void gram_mfma(
    const short* __restrict__ Xh, float* __restrict__ gpart)
{
    const int id = blockIdx.x;
    const int wg = (id & 7) * 72 + (id >> 3);
    const int z = wg / 36;
    const int tri = wg - z * 36;
    int bx = 0;
    #pragma unroll
    for (int b = 1; b < 8; ++b) {
        int base = b * 8 - (b * (b - 1)) / 2;
        if (base <= tri) bx = b;
    }
    const int by = tri - (bx * 8 - (bx * (bx - 1)) / 2) + bx;
    const int k0 = z * GRAMKS;
    const int wave = threadIdx.x >> 6, lane = threadIdx.x & 63;
    const int wr = wave >> 1, wc = wave & 1;
    const int row = lane & 15, koff = (lane >> 4) * 8;
    const short* Ap[4]; const short* Bp[4];
    #pragma unroll
    for (int i = 0; i < 4; ++i) {
        Ap[i] = Xh + (size_t)(bx * 128 + wr * 64 + i * 16 + row) * SROW;
        Bp[i] = Xh + (size_t)(by * 128 + wc * 64 + i * 16 + row) * SROW;
    }
    f32x4 acc[4][4];
    #pragma unroll
    for (int i = 0; i < 4; ++i)
        #pragma unroll
        for (int j = 0; j < 4; ++j) acc[i][j] = (f32x4){0.f,0.f,0.f,0.f};
    bf16x8 a[4], b[4];
    {
        int kk = k0 + koff;
        #pragma unroll
        for (int i = 0; i < 4; ++i) {
            a[i] = *(const bf16x8*)(Ap[i] + kk);
            b[i] = *(const bf16x8*)(Bp[i] + kk);
        }
    }
    for (int k = k0 + 32; k < k0 + GRAMKS; k += 32) {
        bf16x8 an[4], bn[4];
        int kk = k + koff;
        #pragma unroll
        for (int i = 0; i < 4; ++i) {
            an[i] = *(const bf16x8*)(Ap[i] + kk);
            bn[i] = *(const bf16x8*)(Bp[i] + kk);
        }
        #pragma unroll
        for (int i = 0; i < 4; ++i)
            #pragma unroll
            for (int j = 0; j < 4; ++j)
                acc[i][j] = __builtin_amdgcn_mfma_f32_16x16x32_bf16(a[i], b[j], acc[i][j], 0, 0, 0);
        #pragma unroll
        for (int i = 0; i < 4; ++i) { a[i] = an[i]; b[i] = bn[i]; }
    }
    #pragma unroll
    for (int i = 0; i < 4; ++i)
        #pragma unroll
        for (int j = 0; j < 4; ++j)
            acc[i][j] = __builtin_amdgcn_mfma_f32_16x16x32_bf16(a[i], b[j], acc[i][j], 0, 0, 0);
    float* Cb = gpart + ((size_t)z * NTRI + tri) * 16384;
    const int crow = (lane >> 4) * 4;
    const int ccol = lane & 15;
    #pragma unroll
    for (int i = 0; i < 4; ++i) {
        #pragma unroll
        for (int j = 0; j < 4; ++j) {
            int cl = wc * 64 + j * 16 + ccol;
            #pragma unroll
            for (int jj = 0; jj < 4; ++jj) {
                int rl2 = wr * 64 + i * 16 + crow + jj;
                Cb[(size_t)rl2 * 128 + cl] = acc[i][j][jj];
            }
        }
    }
}

// reduce GRAMZ packed-tri partials -> fused dist (with mirror write)
__global__ void gram_reduce_dist(const float* __restrict__ gpart,
                                 const float* __restrict__ sim, const float* __restrict__ sq,
                                 const int* __restrict__ ages, const int* __restrict__ genders,
                                 const float* __restrict__ fscal, float* __restrict__ G)
{
    const int t = blockIdx.x;   // 0..35
    int bx = 0;
    #pragma unroll
    for (int b = 1; b < 8; ++b) {
        int base = b * 8 - (b * (b - 1)) / 2;
        if (base <= t) bx = b;
    }
    const int by = t - (bx * 8 - (bx * (bx - 1)) / 2) + bx;
    int e = blockIdx.y * 1024 + threadIdx.x * 4;
    float sx = 0.f, sy = 0.f, sz = 0.f, sw = 0.f;
    for (int z = 0; z < GRAMZ; ++z) {
        float4 v = *(const float4*)(gpart + ((size_t)z * NTRI + t) * 16384 + e);
        sx += v.x; sy += v.y; sz += v.z; sw += v.w;
    }
    const int i = bx * 128 + (e >> 7), j0 = by * 128 + (e & 127);
    const float smin = fscal[0], smax = fscal[1];
    const float inv = 1.f / (smax - smin);
    const float sqi = sq[i];
    const int agei = ages[i], geni = genders[i];
    float4 simv = *(const float4*)(sim + ((size_t)i << 10) + j0);
    float gs[4] = {sx, sy, sz, sw};
    float sms[4] = {simv.x, simv.y, simv.z, simv.w};
    float out[4];
    #pragma unroll
    for (int c = 0; c < 4; ++c) {
        int j = j0 + c;
        float sn = (sms[c] - smin) * inv;
        float d2 = fmaxf(sqi + sq[j] - 2.f * gs[c], 0.f);
        float fs = expf(-ALPHA * sqrtf(d2));
        float total = fs * (1.f - sn) + sn;
        int da = agei - ages[j]; if (da < 0) da = -da;
        bool cond = (da <= BETAC) && (geni == genders[j]);
        out[c] = total * (cond ? ACOEF : 1.f - ACOEF);
    }
    float4 o = {out[0], out[1], out[2], out[3]};
    *(float4*)(G + ((size_t)i << 10) + j0) = o;
    #pragma unroll
    for (int c = 0; c < 4; ++c)
        G[((size_t)(j0 + c) << 10) + i] = out[c];
}

// p[1024,116] -> row L2-normalize in place
__global__ void rownorm(float* __restrict__ p)
{
    int row = blockIdx.x, t = threadIdx.x;   // 128 threads
    __shared__ float red[128];
    float x = 0.f, v = 0.f;
    if (t < ROIN) { x = p[row * ROIN + t]; v = x * x; }
    red[t] = v; __syncthreads();
    for (int off = 64; off > 0; off >>= 1) { if (t < off) red[t] += red[t + off]; __syncthreads(); }
    float inv = 1.f / sqrtf(red[0]);
    if (t < ROIN) p[row * ROIN + t] = x * inv;
}

// global min/max of sim
__global__ void minmax_part(const float* __restrict__ sim, float* __restrict__ mm)
{
    int t = threadIdx.x, b = blockIdx.x;   // 512 x 256
    float mn = 1e30f, mx = -1e30f;
    for (size_t i = (size_t)b * 256 + t; i < 1048576u; i += 512u * 256u) {
        float v = sim[i]; mn = fminf(mn, v); mx = fmaxf(mx, v);
    }
    __shared__ float smn[256], smx[256];
    smn[t] = mn; smx[t] = mx; __syncthreads();
    for (int off = 128; off > 0; off >>= 1) {
        if (t < off) { smn[t] = fminf(smn[t], smn[t + off]); smx[t] = fmaxf(smx[t], smx[t + off]); }
        __syncthreads();
    }
    if (t == 0) { mm[b] = smn[0]; mm[512 + b] = smx[0]; }
}
__global__ void minmax_final(const float* __restrict__ mm, float* __restrict__ fscal)
{
    int t = threadIdx.x;   // 512 threads
    __shared__ float smn[512], smx[512];
    smn[t] = mm[t]; smx[t] = mm[512 + t]; __syncthreads();
    for (int off = 256; off > 0; off >>= 1) {
        if (t < off) { smn[t] = fminf(smn[t], smn[t + off]); smx[t] = fmaxf(smx[t], smx[t + off]); }
        __syncthreads();
    }
    if (t == 0) { fscal[0] = smn[0]; fscal[1] = smx[0]; }
}

// labels[i] = argmax(site[i,0..3]) (first max)
__global__ void labels_k(const int* __restrict__ site, int* __restrict__ labels)
{
    int i = blockIdx.x * 256 + threadIdx.x;
    if (i >= NBZ) return;
    int best = site[4 * i], bi = 0;
    #pragma unroll
    for (int k = 1; k < 4; ++k) { int v = site[4 * i + k]; if (v > best) { best = v; bi = k; } }
    labels[i] = bi;
}

__global__ void rowcnt_k(const int* __restrict__ labels, int* __restrict__ rowcnt)
{
    int i = blockIdx.x * 256 + threadIdx.x;
    if (i >= NBZ) return;
    int li = labels[i], c = 0;
    for (int j = 0; j < NBZ; ++j) c += (labels[j] == li);
    rowcnt[i] = c;
}

// exclusive scan of per-row positive counts; iscal[0]=npos, iscal[1]=m
__global__ __launch_bounds__(1024) void scan_k(const int* __restrict__ rowcnt,
                                               int* __restrict__ rowoff, int* __restrict__ iscal)
{
    __shared__ int s[1024];
    int t = threadIdx.x;
    int c = rowcnt[t];
    s[t] = c; __syncthreads();
    for (int off = 1; off < 1024; off <<= 1) {
        int v = (t >= off) ? s[t - off] : 0;
        __syncthreads();
        s[t] += v;
        __syncthreads();
    }
    rowoff[t] = s[t] - c;
    if (t == 1023) {
        int npos = s[1023];
        int nneg = 1024 * 1024 - npos;
        iscal[0] = npos;
        iscal[1] = (npos < nneg) ? npos : nneg;
    }
}

// scatter sim values to rank-paired pos/neg arrays
__global__ void pair_scatter(const int* __restrict__ labels, const int* __restrict__ rowoff,
                             const int* __restrict__ iscal, const float* __restrict__ sim,
                             float* __restrict__ posval, float* __restrict__ negval)
{
    int row = blockIdx.x, t = threadIdx.x;
    int m = iscal[1];
    int li = labels[row];
    int j0 = t * 4;
    int eq[4]; int c = 0;
    #pragma unroll
    for (int kk = 0; kk < 4; ++kk) { eq[kk] = (labels[j0 + kk] == li); c += eq[kk]; }
    __shared__ int s[256];
    s[t] = c; __syncthreads();
    for (int off = 1; off < 256; off <<= 1) {
        int v = (t >= off) ? s[t - off] : 0;
        __syncthreads();
        s[t] += v;
        __syncthreads();
    }
    int r = rowoff[row] + s[t] - c;
    size_t base = (size_t)row * 1024;
    #pragma unroll
    for (int kk = 0; kk < 4; ++kk) {
        size_t f = base + j0 + kk;
        float v = sim[f];
        if (eq[kk]) { if (r < m) posval[r] = v; r++; }
        else { long nr = (long)f - r; if (nr < m) negval[nr] = v; }
    }
}

__global__ void loss_part(const float* __restrict__ posval, const float* __restrict__ negval,
                          const int* __restrict__ iscal, float* __restrict__ lp)
{
    int m = iscal[1];
    int t = threadIdx.x, b = blockIdx.x;   // 1024 x 256
    float s = 0.f;
    for (int k = b * 256 + t; k < m; k += 1024 * 256) {
        float d = negval[k] - posval[k];
        s += fmaxf(d, 0.f) + log1pf(expf(-fabsf(d)));
    }
    __shared__ float red[256];
    red[t] = s; __syncthreads();
    for (int off = 128; off > 0; off >>= 1) { if (t < off) red[t] += red[t + off]; __syncthreads(); }
    if (t == 0) lp[b] = red[0];
}

__global__ void loss_final(const float* __restrict__ lp, const int* __restrict__ iscal,
                           float* __restrict__ outp)
{
    int t = threadIdx.x;   // 256
    double s = 0.0;
    for (int k = t; k < 1024; k += 256) s += (double)lp[k];
    __shared__ double red[256];
    red[t] = s; __syncthreads();
    for (int off = 128; off > 0; off >>= 1) { if (t < off) red[t] += red[t + off]; __syncthreads(); }
    if (t == 0) {
        int m = iscal[1]; if (m < 1) m = 1;
        outp[0] = (float)(red[0] / (double)m);
    }
}

// row-wise top-8 (ties -> lower index)
__global__ void topk8(const float* __restrict__ dist, float* __restrict__ topv, int* __restrict__ topi)
{
    int row = blockIdx.x, t = threadIdx.x;
    __shared__ float sv[1024];
    __shared__ float rv[256];
    __shared__ int   ri[256];
    for (int j = t; j < 1024; j += 256) sv[j] = dist[(size_t)row * 1024 + j];
    __syncthreads();
    for (int k = 0; k < 8; ++k) {
        float bv = -1e30f; int bi = 1 << 20;
        for (int j = t; j < 1024; j += 256) {
            float x = sv[j];
            if (x > bv || (x == bv && j < bi)) { bv = x; bi = j; }
        }
        rv[t] = bv; ri[t] = bi;
        __syncthreads();
        for (int s = 128; s > 0; s >>= 1) {
            if (t < s) {
                float ov = rv[t + s]; int oi = ri[t + s];
                if (ov > rv[t] || (ov == rv[t] && oi < ri[t])) { rv[t] = ov; ri[t] = oi; }
            }
            __syncthreads();
        }
        if (t == 0) { topv[row * 8 + k] = rv[0]; topi[row * 8 + k] = ri[0]; sv[ri[0]] = -1e30f; }
        __syncthreads();
    }
}

// bn3: per-ROI-channel stats over (N=1024, L=8); writes final output
__global__ void bn3_k(const float* __restrict__ X, const float* __restrict__ g,
                      const float* __restrict__ bta, float* __restrict__ out)
{
    int c = blockIdx.x, t = threadIdx.x;   // 116 x 256
    float s = 0.f, s2 = 0.f;
    for (int k = t; k < 8192; k += 256) {
        int n = k >> 3, l = k & 7;
        float v = X[(size_t)n * 928 + c * 8 + l];
        s += v; s2 += v * v;
    }
    __shared__ float rs[256], rs2[256];
    rs[t] = s; rs2[t] = s2; __syncthreads();
    for (int off = 128; off > 0; off >>= 1) {
        if (t < off) { rs[t] += rs[t + off]; rs2[t] += rs2[t + off]; }
        __syncthreads();
    }
    __shared__ float sm, sr;
    if (t == 0) {
        float mean = rs[0] / 8192.f;
        float var = rs2[0] / 8192.f - mean * mean;
        sm = mean; sr = 1.f / sqrtf(var + EPSBN);
    }
    __syncthreads();
    float mean = sm, rstd = sr, gg = g[c], bb = bta[c];
    for (int k = t; k < 8192; k += 256) {
        int n = k >> 3, l = k & 7;
        size_t idx = (size_t)n * 928 + c * 8 + l;
        out[idx] = (X[idx] - mean) * rstd * gg + bb;
    }
}

// ---------------------------------------------------------------------------
extern "C" void kernel_launch(void* const* d_in, const int* in_sizes, int n_in,
                              void* d_out, int out_size, void* d_ws, size_t ws_size,
                              hipStream_t stream)
{
    const float* x        = (const float*)d_in[0];
    const float* pseudo   = (const float*)d_in[1];
    const int*   ages     = (const int*)d_in[2];
    const int*   genders  = (const int*)d_in[3];
    const int*   site     = (const int*)d_in[4];
    const float* fc_p_w   = (const float*)d_in[5];
    const float* fc_p_b   = (const float*)d_in[6];
    const float* proj_w1  = (const float*)d_in[7];
    const float* proj_b1  = (const float*)d_in[8];
    const float* proj_w2  = (const float*)d_in[9];
    const float* proj_b2  = (const float*)d_in[10];
    const float* gcn_w1   = (const float*)d_in[11];
    const float* gcn_b1   = (const float*)d_in[12];
    const float* gcn_w2   = (const float*)d_in[13];
    const float* gcn_b2   = (const float*)d_in[14];
    const float* gcn1_w   = (const float*)d_in[15];
    const float* gcn1_b   = (const float*)d_in[16];
    const float* gcn2_w1  = (const float*)d_in[17];
    const float* gcn2_b1  = (const float*)d_in[18];
    const float* gcn2_w2  = (const float*)d_in[19];
    const float* gcn2_b2  = (const float*)d_in[20];
    const float* bn1_g    = (const float*)d_in[21];
    const float* bn1_b    = (const float*)d_in[22];
    const float* bn2_g    = (const float*)d_in[23];
    const float* bn2_b    = (const float*)d_in[24];
    const float* bn3_g    = (const float*)d_in[25];
    const float* bn3_b    = (const float*)d_in[26];
    float* dout = (float*)d_out;

    char* w = (char*)d_ws;
    size_t off = 0;
    auto carve = [&](size_t bytes) { char* p = w + off; off = (off + bytes + 255) & ~(size_t)255; return p; };
    float* xf     = (float*)carve((size_t)NROWS * LDF * 4);   // 58.0 MB padded
    float* hA     = (float*)carve((size_t)NROWS * LDF * 4);
    float* hB     = (float*)carve((size_t)NROWS * LDF * 4);
    float* G      = (float*)carve(1048576u * 4);
    float* simb   = (float*)carve(1048576u * 4);
    float* t1     = (float*)carve((size_t)NBZ * ROIN * 4);
    float* pbuf   = (float*)carve((size_t)NBZ * ROIN * 4);
    float* sq     = (float*)carve(4096);
    float* rsq    = (float*)carve((size_t)NROWS * 4);
    int*   labels = (int*)carve(4096);
    int*   rowcnt = (int*)carve(4096);
    int*   rowoff = (int*)carve(4096);
    int*   iscal  = (int*)carve(256);
    float* fscal  = (float*)carve(256);
    float* posval = (float*)carve(524288u * 4);
    float* negval = (float*)carve(524288u * 4);
    float* lpart  = (float*)carve(4096);
    float* mmpart = (float*)carve(4096);
    float* topv   = (float*)carve(32768);
    int*   topi   = (int*)carve(32768);
    float* statp  = (float*)carve((size_t)232 * GX2 * 4);
    float* sbAp   = (float*)carve(512);
    float* tbAp   = (float*)carve(512);
    float* sbBp   = (float*)carve(512);
    float* tbBp   = (float*)carve(512);
    short* wt1_hi = (short*)carve((size_t)128 * W1LD * 2);    // 3.8 MB
    short* wt1_lo = (short*)carve((size_t)128 * W1LD * 2);
    short* wts    = (short*)carve((size_t)7 * 2 * 16384 * 2);
    // aliases into dead phases:
    float* ppart  = hA;                                 // proj1 partials (13.8 MB)
    float* gpart  = hA;                                 // Gram partials 16*36*64KB = 37.7 MB
    short* xfh    = (short*)((char*)hB + (16u << 20));  // bf16 xf 30.4 MB at hB+16MB
    short* actH1  = (short*)hA;                         // 29.7 MB (gpart dead)
    short* actH2  = (short*)hB;                         // 29.7 MB (xfh dead after wg1)
    short* actH3  = (short*)hA;                         // 29.7 MB (actH1 dead)
    float* h45    = hB;                                 // 3.8 MB (actH2 dead)

    auto wt_hi = [&](int i) { return wts + (size_t)i * 2 * 16384; };
    auto wt_lo = [&](int i) { return wts + (size_t)i * 2 * 16384 + 16384; };

    // 0. weight pretranspose + hi/lo split (PERM for bf16-permuted-A consumers)
    wt1_conv<<<(128 * W1LD) / 256, 256, 0, stream>>>(proj_w1, wt1_hi, wt1_lo);
    wt_conv<false><<<64, 256, 0, stream>>>(fc_p_w,  wt_hi(0), wt_lo(0), 116, 116);
    wt_conv<false><<<64, 256, 0, stream>>>(proj_w2, wt_hi(1), wt_lo(1), 116, 116);
    wt_conv<true ><<<64, 256, 0, stream>>>(gcn_w1,  wt_hi(2), wt_lo(2), 116, 116);
    wt_conv<true ><<<64, 256, 0, stream>>>(gcn_w2,  wt_hi(3), wt_lo(3), 116, 116);
    wt_conv<true ><<<64, 256, 0, stream>>>(gcn1_w,  wt_hi(4), wt_lo(4), 116, 116);
    wt_conv<true ><<<64, 256, 0, stream>>>(gcn2_w1, wt_hi(5), wt_lo(5), 116, 64);
    wt_conv<false><<<64, 256, 0, stream>>>(gcn2_w2, wt_hi(6), wt_lo(6), 64, 8);

    // 1. xf = x + leaky(pseudo @ fc_p_w + b) padded; permuted bf16 xfh + row sumsq
    mfma_gemm_w<4, 1, false><<<GX2, 512, 0, stream>>>(pseudo, wt_hi(0), wt_lo(0), fc_p_b, x, xf,
                                                      xfh, rsq, ROIN, LDF);
    sq_reduce<<<4, 256, 0, stream>>>(rsq, sq);

    // 2. proj head
    mfma_proj1<<<dim3(16, 1, PZ), 256, 0, stream>>>(xf, wt1_hi, wt1_lo, ppart);
    proj_reduce<<<(NBZ * ROIN + 255) / 256, 256, 0, stream>>>(ppart, proj_b1, t1);
    mfma_gemm_w<1, 0, false><<<8, 512, 0, stream>>>(t1, wt_hi(1), wt_lo(1), proj_b2, nullptr, pbuf,
                                                    nullptr, nullptr, ROIN, ROIN);
    rownorm<<<NBZ, 128, 0, stream>>>(pbuf);

    // 3. sim = (pn @ pn^T) / TEMP
    gemm_nt_sym<<<dim3(16, 16, 1), 256, 0, stream>>>(pbuf, simb, NBZ, ROIN, 1.f / 0.07f);

    // 4. contrastive loss
    labels_k<<<4, 256, 0, stream>>>(site, labels);
    rowcnt_k<<<4, 256, 0, stream>>>(labels, rowcnt);
    scan_k<<<1, 1024, 0, stream>>>(rowcnt, rowoff, iscal);
    pair_scatter<<<NBZ, 256, 0, stream>>>(labels, rowoff, iscal, simb, posval, negval);
    loss_part<<<1024, 256, 0, stream>>>(posval, negval, iscal, lpart);
    loss_final<<<1, 256, 0, stream>>>(lpart, iscal, dout + (size_t)NBZ * ROIN * 8);

    // 5. sim min/max, Gram (XCD-affine), fused reduce+dist, top-k
    minmax_part<<<512, 256, 0, stream>>>(simb, mmpart);
    minmax_final<<<1, 512, 0, stream>>>(mmpart, fscal);
    gram_mfma<<<NTRI * GRAMZ, 256, 0, stream>>>(xfh, gpart);
    gram_reduce_dist<<<dim3(NTRI, 16), 256, 0, stream>>>(gpart, simb, sq, ages, genders, fscal, G);
    topk8<<<NBZ, 256, 0, stream>>>(G, topv, topi);

    // 6. GCN stack on bf16-permuted activations (weights & BN vectors permuted)
    mfma_gemm_wg_h<0, false><<<GX2, 512, 0, stream>>>(topv, topi, xfh, nullptr, nullptr,
                                                      wt_hi(2), wt_lo(2), gcn_b1, actH1, nullptr);
    mfma_gemm_bA<<<GX2, 512, 0, stream>>>(actH1, wt_hi(3), wt_lo(3), gcn_b2, actH2, statp);
    bn_final_st_p<<<128, 256, 0, stream>>>(statp, bn1_g, bn1_b, sbAp, tbAp, GX2);

    mfma_gemm_wg_h<2, true><<<GX2, 512, 0, stream>>>(topv, topi, actH2, sbAp, tbAp,
                                                     wt_hi(4), wt_lo(4), gcn1_b, actH3, statp);
    bn_final_st_p<<<128, 256, 0, stream>>>(statp, bn2_g, bn2_b, sbBp, tbBp, GX2);

    mfma_gemm45_wg_h<<<GX45, 256, 0, stream>>>(topv, topi, actH3, sbBp, tbBp,
                                               wt_hi(5), wt_lo(5), gcn2_b1,
                                               wt_hi(6), wt_lo(6), gcn2_b2, h45);

    // 7. bn3 -> d_out
    bn3_k<<<116, 256, 0, stream>>>(h45, bn3_g, bn3_b, dout);
}

// Round 18
// 553.286 us; speedup vs baseline: 1.0837x; 1.0644x over previous
//
#include <hip/hip_runtime.h>
#include <math.h>

#define ROIN 116
#define NBZ 1024
#define LDF 128            // padded ROI-row length (floats / bf16)
#define SROW (ROIN*LDF)    // 14848: padded per-sample flat row
#define NROWS (NBZ*ROIN)   // 118784
#define ALPHA 0.1f
#define ACOEF 0.9f
#define BETAC 2
#define EPSBN 1e-5f
#define PZ 29              // proj1 split-K chunks (29*512 = 14848)
#define PCH 512
#define W1LD SROW
#define GX2 928            // NROWS/128 (512-thread GEMM blocks)
#define GX45 1856          // NROWS/64 (gemm45 blocks)
#define GRAMZ 16
#define GRAMKS 928         // 16*928 = 14848
#define NTRI 36            // upper-tri 128x128 tiles of 8x8 grid

typedef __attribute__((ext_vector_type(8))) short bf16x8;
typedef __attribute__((ext_vector_type(4))) float f32x4;

__device__ __forceinline__ float leakyf(float v){ return v >= 0.f ? v : 0.2f*v; }

__device__ __forceinline__ short f2bf(float f){
    unsigned u = __builtin_bit_cast(unsigned, f);
    unsigned r = u + 0x7fffu + ((u >> 16) & 1u);   // RNE
    return (short)(r >> 16);
}
__device__ __forceinline__ float bf2f(short h){
    unsigned u = ((unsigned)(unsigned short)h) << 16;
    return __builtin_bit_cast(float, u);
}

// Column permutation used by all bf16-permuted activation emits:
// logical col c -> stored col (c&15)*8 + (c>>4)   (bijection on [0,128))
// Inverse: stored kp -> logical (kp&7)*16 + (kp>>3).

// ---------------------------------------------------------------------------
// Weight pretranspose + bf16 hi/lo split. Small weights -> WT[128][128].
// PERM: permute K-dim to match permuted bf16 activations.
// ---------------------------------------------------------------------------
template<bool PERM>
__global__ void wt_conv(const float* __restrict__ W, short* __restrict__ hi,
                        short* __restrict__ lo, int K, int N)
{
    int idx = blockIdx.x * 256 + threadIdx.x;   // 16384
    int n = idx >> 7, kp = idx & 127;
    int k = PERM ? ((kp & 7) * 16 + (kp >> 3)) : kp;
    float v = (n < N && k < K) ? W[(size_t)k * N + n] : 0.f;
    short h = f2bf(v);
    hi[idx] = h;
    lo[idx] = f2bf(v - bf2f(h));
}

// proj_w1 [13456,116] -> WT1[128][14848] hi/lo; K permuted within each
// 128-block to match the permuted bf16 xfh/xfl: slot kp holds logical
// d=(kp&7)*16+(kp>>3)
__global__ void wt1_conv(const float* __restrict__ W, short* __restrict__ hi,
                         short* __restrict__ lo)
{
    int idx = blockIdx.x * 256 + threadIdx.x;   // 128*14848
    int n = idx / W1LD, k = idx - n * W1LD;
    int r = k >> 7, dp = k & 127;
    int d = (dp & 7) * 16 + (dp >> 3);
    float v = (n < ROIN && d < ROIN) ? W[(size_t)(r * ROIN + d) * ROIN + n] : 0.f;
    short h = f2bf(v);
    hi[idx] = h;
    lo[idx] = f2bf(v - bf2f(h));
}

// ---------------------------------------------------------------------------
// bf16x2 MFMA GEMM, 512 threads, 128 rows/block, LDS-staged weights.
// EPI: 1 bias, 3 leaky(bias), 4 X + leaky(bias)
// XTRA: 0 none (fp32 C [m][n], guarded n<LDC);
//       1 emit permuted bf16 HI+LO (no fp32 C) + row sumsq
// ---------------------------------------------------------------------------
template<int EPI, int XTRA, bool PADK>
__global__ __launch_bounds__(512) void mfma_gemm_w(
    const float* __restrict__ A, const short* __restrict__ wt_hi,
    const short* __restrict__ wt_lo, const float* __restrict__ bias,
    const float* __restrict__ X, float* __restrict__ C,
    short* __restrict__ bfout, short* __restrict__ bflo, float* __restrict__ rsq,
    int LDA, int LDC)
{
    __shared__ short whi[128][136];
    __shared__ short wlo[128][136];
    const int tid = threadIdx.x;
    {
        int r = tid >> 2, q = tid & 3;
        const short* sh = wt_hi + r * 128 + q * 32;
        const short* sl = wt_lo + r * 128 + q * 32;
        #pragma unroll
        for (int i = 0; i < 4; ++i) {
            *(bf16x8*)(&whi[r][q * 32 + i * 8]) = *(const bf16x8*)(sh + i * 8);
            *(bf16x8*)(&wlo[r][q * 32 + i * 8]) = *(const bf16x8*)(sl + i * 8);
        }
    }
    __syncthreads();
    const int wave = tid >> 6, lane = tid & 63;
    const int m0 = blockIdx.x * 128 + wave * 16;
    const int rl = lane & 15, g = lane >> 4;
    const float* Arow = A + (size_t)(m0 + rl) * LDA;
    float av[4][8];
    #pragma unroll
    for (int s = 0; s < 4; ++s) {
        const int kk = s * 32 + g * 8;
        if (PADK || kk + 8 <= ROIN) {
            float4 p = *(const float4*)(Arow + kk);
            float4 q = *(const float4*)(Arow + kk + 4);
            av[s][0]=p.x; av[s][1]=p.y; av[s][2]=p.z; av[s][3]=p.w;
            av[s][4]=q.x; av[s][5]=q.y; av[s][6]=q.z; av[s][7]=q.w;
        } else if (kk + 4 <= ROIN) {
            float4 p = *(const float4*)(Arow + kk);
            av[s][0]=p.x; av[s][1]=p.y; av[s][2]=p.z; av[s][3]=p.w;
            av[s][4]=0.f; av[s][5]=0.f; av[s][6]=0.f; av[s][7]=0.f;
        } else {
            #pragma unroll
            for (int j = 0; j < 8; ++j) av[s][j] = 0.f;
        }
    }
    f32x4 acc[8];
    #pragma unroll
    for (int nf = 0; nf < 8; ++nf) acc[nf] = (f32x4){0.f,0.f,0.f,0.f};
    #pragma unroll
    for (int s = 0; s < 4; ++s) {
        const int kk = s * 32 + g * 8;
        bf16x8 ah, al;
        #pragma unroll
        for (int j = 0; j < 8; ++j) {
            short h = f2bf(av[s][j]); ah[j] = h;
            al[j] = f2bf(av[s][j] - bf2f(h));
        }
        #pragma unroll
        for (int nf = 0; nf < 8; ++nf) {
            const bf16x8 bh = *(const bf16x8*)(&whi[nf * 16 + rl][kk]);
            const bf16x8 bl = *(const bf16x8*)(&wlo[nf * 16 + rl][kk]);
            acc[nf] = __builtin_amdgcn_mfma_f32_16x16x32_bf16(ah, bh, acc[nf], 0, 0, 0);
            acc[nf] = __builtin_amdgcn_mfma_f32_16x16x32_bf16(al, bh, acc[nf], 0, 0, 0);
            acc[nf] = __builtin_amdgcn_mfma_f32_16x16x32_bf16(ah, bl, acc[nf], 0, 0, 0);
        }
    }
    const int cm = g * 4;
    if (XTRA == 1) {
        bf16x8 bfh[4], bfl[4];
        float rq[4] = {0.f, 0.f, 0.f, 0.f};
        #pragma unroll
        for (int nf = 0; nf < 8; ++nf) {
            int n = nf * 16 + rl;
            float bb = (n < ROIN) ? bias[n] : 0.f;
            #pragma unroll
            for (int j = 0; j < 4; ++j) {
                int m = m0 + cm + j;
                float v = 0.f;
                if (n < ROIN) {
                    v = acc[nf][j] + bb;
                    if (EPI == 3) v = leakyf(v);
                    else if (EPI == 4) v = X[(size_t)m * LDA + n] + leakyf(v);
                }
                short h = f2bf(v);
                bfh[j][nf] = h;
                bfl[j][nf] = f2bf(v - bf2f(h));
                rq[j] += v * v;
            }
        }
        #pragma unroll
        for (int j = 0; j < 4; ++j) {
            *(bf16x8*)(&bfout[(size_t)(m0 + cm + j) * LDF + rl * 8]) = bfh[j];
            *(bf16x8*)(&bflo[(size_t)(m0 + cm + j) * LDF + rl * 8]) = bfl[j];
        }
        #pragma unroll
        for (int j = 0; j < 4; ++j) {
            rq[j] += __shfl_xor(rq[j], 1);
            rq[j] += __shfl_xor(rq[j], 2);
            rq[j] += __shfl_xor(rq[j], 4);
            rq[j] += __shfl_xor(rq[j], 8);
        }
        if (rl == 0) {
            #pragma unroll
            for (int j = 0; j < 4; ++j) rsq[m0 + cm + j] = rq[j];
        }
    } else {
        #pragma unroll
        for (int nf = 0; nf < 8; ++nf) {
            int n = nf * 16 + rl;
            float bb = (n < ROIN) ? bias[n] : 0.f;
            #pragma unroll
            for (int j = 0; j < 4; ++j) {
                int m = m0 + cm + j;
                float v = 0.f;
                if (n < ROIN) {
                    v = acc[nf][j] + bb;
                    if (EPI == 3) v = leakyf(v);
                    else if (EPI == 4) v = X[(size_t)m * LDA + n] + leakyf(v);
                }
                if (n < LDC) C[(size_t)m * LDC + n] = v;
            }
        }
    }
}

// ---------------------------------------------------------------------------
// Gather-fused GEMM on bf16-permuted activations (pipelined gather).
// feat: bf16 permuted rows [NROWS][128]; weights K-permuted; sbP/tbP permuted
// (zeros at pad slots). Emits bf16-permuted out (+BN stats if XTRA==2).
// Epilogue: leaky(acc + bias).
// ---------------------------------------------------------------------------
template<int XTRA, bool FOLD>
__global__ __launch_bounds__(512, 4) void mfma_gemm_wg_h(
    const float* __restrict__ vals, const int* __restrict__ idxs,
    const short* __restrict__ feat, const float* __restrict__ sbP,
    const float* __restrict__ tbP,
    const short* __restrict__ wt_hi, const short* __restrict__ wt_lo,
    const float* __restrict__ bias, short* __restrict__ outH,
    float* __restrict__ statp)
{
    __shared__ short whi[128][136];
    __shared__ short wlo[128][136];
    __shared__ float st[(XTRA == 2) ? 8 : 1][2][128];
    const int tid = threadIdx.x;
    {
        int r = tid >> 2, q = tid & 3;
        const short* sh = wt_hi + r * 128 + q * 32;
        const short* sl = wt_lo + r * 128 + q * 32;
        #pragma unroll
        for (int i = 0; i < 4; ++i) {
            *(bf16x8*)(&whi[r][q * 32 + i * 8]) = *(const bf16x8*)(sh + i * 8);
            *(bf16x8*)(&wlo[r][q * 32 + i * 8]) = *(const bf16x8*)(sl + i * 8);
        }
    }
    __syncthreads();
    const int wave = tid >> 6, lane = tid & 63;
    const int m0 = blockIdx.x * 128 + wave * 16;
    const int rl = lane & 15, g = lane >> 4;
    const int m = m0 + rl;
    const unsigned bz = (unsigned)m / 116u;
    const int r = m - (int)bz * 116;
    float vv[8]; const short* fp[8];
    #pragma unroll
    for (int k = 0; k < 8; ++k) {
        vv[k] = vals[bz * 8 + k];
        int ixk = idxs[bz * 8 + k];
        fp[k] = feat + ((size_t)ixk * 116 + r) * 128;
    }
    float wsum = 0.f;
    if (FOLD) {
        #pragma unroll
        for (int k = 0; k < 8; ++k) wsum += vv[k];
    }
    f32x4 acc[8];
    #pragma unroll
    for (int nf = 0; nf < 8; ++nf) acc[nf] = (f32x4){0.f,0.f,0.f,0.f};
    bf16x8 xb[8], xn[8];
    #pragma unroll
    for (int k = 0; k < 8; ++k) xb[k] = *(const bf16x8*)(fp[k] + g * 8);
    #pragma unroll
    for (int s = 0; s < 4; ++s) {
        const int kk = s * 32 + g * 8;
        if (s < 3) {
            #pragma unroll
            for (int k = 0; k < 8; ++k) xn[k] = *(const bf16x8*)(fp[k] + kk + 32);
        }
        float av[8] = {0.f,0.f,0.f,0.f,0.f,0.f,0.f,0.f};
        #pragma unroll
        for (int k = 0; k < 8; ++k) {
            const float vk = vv[k];
            #pragma unroll
            for (int j = 0; j < 8; ++j) av[j] = fmaf(vk, bf2f(xb[k][j]), av[j]);
        }
        if (FOLD) {
            #pragma unroll
            for (int j = 0; j < 8; ++j)
                av[j] = sbP[kk + j] * av[j] + wsum * tbP[kk + j];   // pads: 0*0+w*0=0
        }
        bf16x8 ah, al;
        #pragma unroll
        for (int j = 0; j < 8; ++j) {
            short h = f2bf(av[j]); ah[j] = h;
            al[j] = f2bf(av[j] - bf2f(h));
        }
        __builtin_amdgcn_s_setprio(1);
        #pragma unroll
        for (int nf = 0; nf < 8; ++nf) {
            const bf16x8 bh = *(const bf16x8*)(&whi[nf * 16 + rl][kk]);
            const bf16x8 bl = *(const bf16x8*)(&wlo[nf * 16 + rl][kk]);
            acc[nf] = __builtin_amdgcn_mfma_f32_16x16x32_bf16(ah, bh, acc[nf], 0, 0, 0);
            acc[nf] = __builtin_amdgcn_mfma_f32_16x16x32_bf16(al, bh, acc[nf], 0, 0, 0);
            acc[nf] = __builtin_amdgcn_mfma_f32_16x16x32_bf16(ah, bl, acc[nf], 0, 0, 0);
        }
        __builtin_amdgcn_s_setprio(0);
        #pragma unroll
        for (int k = 0; k < 8; ++k) xb[k] = xn[k];
    }
    const int cm = g * 4;
    bf16x8 bfv[4];
    #pragma unroll
    for (int nf = 0; nf < 8; ++nf) {
        int n = nf * 16 + rl;
        float c1 = 0.f, c2 = 0.f;
        float bb = (n < ROIN) ? bias[n] : 0.f;
        #pragma unroll
        for (int j = 0; j < 4; ++j) {
            float v = 0.f;
            if (n < ROIN) v = leakyf(acc[nf][j] + bb);
            bfv[j][nf] = f2bf(v);
            if (XTRA == 2) { c1 += v; c2 += v * v; }
        }
        if (XTRA == 2) {
            c1 += __shfl_xor(c1, 16); c1 += __shfl_xor(c1, 32);
            c2 += __shfl_xor(c2, 16); c2 += __shfl_xor(c2, 32);
            if (lane < 16) { st[wave][0][n & 127] = c1; st[wave][1][n & 127] = c2; }
        }
    }
    #pragma unroll
    for (int j = 0; j < 4; ++j)
        *(bf16x8*)(&outH[(size_t)(m0 + cm + j) * LDF + rl * 8]) = bfv[j];
    if (XTRA == 2) {
        __syncthreads();
        if (tid < 232) {
            int sel = tid < 116 ? 0 : 1;
            int c = sel ? tid - 116 : tid;
            float s = 0.f;
            #pragma unroll
            for (int wv = 0; wv < 8; ++wv) s += st[wv][sel][c];
            statp[(size_t)(sel * 116 + c) * GX2 + blockIdx.x] = s;
        }
    }
}

// ---------------------------------------------------------------------------
// bf16-A GEMM (gcn_w2): A = bf16 permuted rows; weights K-permuted.
// C = A@W + bias (no leaky). Emits bf16-permuted out + BN1 stats.
// ---------------------------------------------------------------------------
__global__ __launch_bounds__(512) void mfma_gemm_bA(
    const short* __restrict__ A,
    const short* __restrict__ wt_hi, const short* __restrict__ wt_lo,
    const float* __restrict__ bias, short* __restrict__ outH,
    float* __restrict__ statp)
{
    __shared__ short whi[128][136];
    __shared__ short wlo[128][136];
    __shared__ float st[8][2][128];
    const int tid = threadIdx.x;
    {
        int r = tid >> 2, q = tid & 3;
        const short* sh = wt_hi + r * 128 + q * 32;
        const short* sl = wt_lo + r * 128 + q * 32;
        #pragma unroll
        for (int i = 0; i < 4; ++i) {
            *(bf16x8*)(&whi[r][q * 32 + i * 8]) = *(const bf16x8*)(sh + i * 8);
            *(bf16x8*)(&wlo[r][q * 32 + i * 8]) = *(const bf16x8*)(sl + i * 8);
        }
    }
    __syncthreads();
    const int wave = tid >> 6, lane = tid & 63;
    const int m0 = blockIdx.x * 128 + wave * 16;
    const int rl = lane & 15, g = lane >> 4;
    const short* Arow = A + (size_t)(m0 + rl) * LDF;
    bf16x8 av[4];
    #pragma unroll
    for (int s = 0; s < 4; ++s) av[s] = *(const bf16x8*)(Arow + s * 32 + g * 8);
    f32x4 acc[8];
    #pragma unroll
    for (int nf = 0; nf < 8; ++nf) acc[nf] = (f32x4){0.f,0.f,0.f,0.f};
    #pragma unroll
    for (int s = 0; s < 4; ++s) {
        const int kk = s * 32 + g * 8;
        const bf16x8 ah = av[s];
        #pragma unroll
        for (int nf = 0; nf < 8; ++nf) {
            const bf16x8 bh = *(const bf16x8*)(&whi[nf * 16 + rl][kk]);
            const bf16x8 bl = *(const bf16x8*)(&wlo[nf * 16 + rl][kk]);
            acc[nf] = __builtin_amdgcn_mfma_f32_16x16x32_bf16(ah, bh, acc[nf], 0, 0, 0);
            acc[nf] = __builtin_amdgcn_mfma_f32_16x16x32_bf16(ah, bl, acc[nf], 0, 0, 0);
        }
    }
    const int cm = g * 4;
    bf16x8 bfv[4];
    #pragma unroll
    for (int nf = 0; nf < 8; ++nf) {
        int n = nf * 16 + rl;
        float c1 = 0.f, c2 = 0.f;
        float bb = (n < ROIN) ? bias[n] : 0.f;
        #pragma unroll
        for (int j = 0; j < 4; ++j) {
            float v = 0.f;
            if (n < ROIN) v = acc[nf][j] + bb;
            bfv[j][nf] = f2bf(v);
            c1 += v; c2 += v * v;
        }
        c1 += __shfl_xor(c1, 16); c1 += __shfl_xor(c1, 32);
        c2 += __shfl_xor(c2, 16); c2 += __shfl_xor(c2, 32);
        if (lane < 16) { st[wave][0][n & 127] = c1; st[wave][1][n & 127] = c2; }
    }
    #pragma unroll
    for (int j = 0; j < 4; ++j)
        *(bf16x8*)(&outH[(size_t)(m0 + cm + j) * LDF + rl * 8]) = bfv[j];
    __syncthreads();
    if (tid < 232) {
        int sel = tid < 116 ? 0 : 1;
        int c = sel ? tid - 116 : tid;
        float s = 0.f;
        #pragma unroll
        for (int wv = 0; wv < 8; ++wv) s += st[wv][sel][c];
        statp[(size_t)(sel * 116 + c) * GX2 + blockIdx.x] = s;
    }
}

// ---------------------------------------------------------------------------
// Gather-fused pair on bf16-permuted activations:
// C[NROWS][8] = leaky(leaky(BN-gath @ W5(perm) + b5) @ W6 + b6)
// ---------------------------------------------------------------------------
__global__ __launch_bounds__(256) void mfma_gemm45_wg_h(
    const float* __restrict__ vals, const int* __restrict__ idxs,
    const short* __restrict__ feat, const float* __restrict__ sbP,
    const float* __restrict__ tbP,
    const short* __restrict__ w5h, const short* __restrict__ w5l,
    const float* __restrict__ b5,
    const short* __restrict__ w6h, const short* __restrict__ w6l,
    const float* __restrict__ b6,
    float* __restrict__ C)
{
    __shared__ short s5h[64][136], s5l[64][136];
    __shared__ short s6h[16][136], s6l[16][136];
    __shared__ float c1s[4][16][76];
    const int tid = threadIdx.x;
    {
        int r = tid >> 2, q = tid & 3;
        const short* sh = w5h + r * 128 + q * 32;
        const short* sl = w5l + r * 128 + q * 32;
        #pragma unroll
        for (int i = 0; i < 4; ++i) {
            *(bf16x8*)(&s5h[r][q * 32 + i * 8]) = *(const bf16x8*)(sh + i * 8);
            *(bf16x8*)(&s5l[r][q * 32 + i * 8]) = *(const bf16x8*)(sl + i * 8);
        }
        if (tid < 64) {
            int r6 = tid >> 2, q6 = tid & 3;
            const short* sh6 = w6h + r6 * 128 + q6 * 32;
            const short* sl6 = w6l + r6 * 128 + q6 * 32;
            #pragma unroll
            for (int i = 0; i < 4; ++i) {
                *(bf16x8*)(&s6h[r6][q6 * 32 + i * 8]) = *(const bf16x8*)(sh6 + i * 8);
                *(bf16x8*)(&s6l[r6][q6 * 32 + i * 8]) = *(const bf16x8*)(sl6 + i * 8);
            }
        }
    }
    __syncthreads();
    const int wave = tid >> 6, lane = tid & 63;
    const int m0 = blockIdx.x * 64 + wave * 16;
    const int rl = lane & 15, g = lane >> 4;
    const int m = m0 + rl;
    const unsigned bz = (unsigned)m / 116u;
    const int r = m - (int)bz * 116;
    float vv[8]; const short* fp[8];
    #pragma unroll
    for (int k = 0; k < 8; ++k) {
        vv[k] = vals[bz * 8 + k];
        int ixk = idxs[bz * 8 + k];
        fp[k] = feat + ((size_t)ixk * 116 + r) * 128;
    }
    float wsum = 0.f;
    #pragma unroll
    for (int k = 0; k < 8; ++k) wsum += vv[k];
    f32x4 acc[4];
    #pragma unroll
    for (int nf = 0; nf < 4; ++nf) acc[nf] = (f32x4){0.f,0.f,0.f,0.f};
    bf16x8 xb[8], xn[8];
    #pragma unroll
    for (int k = 0; k < 8; ++k) xb[k] = *(const bf16x8*)(fp[k] + g * 8);
    #pragma unroll
    for (int s = 0; s < 4; ++s) {
        const int kk = s * 32 + g * 8;
        if (s < 3) {
            #pragma unroll
            for (int k = 0; k < 8; ++k) xn[k] = *(const bf16x8*)(fp[k] + kk + 32);
        }
        float av[8] = {0.f,0.f,0.f,0.f,0.f,0.f,0.f,0.f};
        #pragma unroll
        for (int k = 0; k < 8; ++k) {
            const float vk = vv[k];
            #pragma unroll
            for (int j = 0; j < 8; ++j) av[j] = fmaf(vk, bf2f(xb[k][j]), av[j]);
        }
        #pragma unroll
        for (int j = 0; j < 8; ++j)
            av[j] = sbP[kk + j] * av[j] + wsum * tbP[kk + j];
        bf16x8 ah, al;
        #pragma unroll
        for (int j = 0; j < 8; ++j) {
            short h = f2bf(av[j]); ah[j] = h;
            al[j] = f2bf(av[j] - bf2f(h));
        }
        __builtin_amdgcn_s_setprio(1);
        #pragma unroll
        for (int nf = 0; nf < 4; ++nf) {
            const bf16x8 bh = *(const bf16x8*)(&s5h[nf * 16 + rl][kk]);
            const bf16x8 bl = *(const bf16x8*)(&s5l[nf * 16 + rl][kk]);
            acc[nf] = __builtin_amdgcn_mfma_f32_16x16x32_bf16(ah, bh, acc[nf], 0, 0, 0);
            acc[nf] = __builtin_amdgcn_mfma_f32_16x16x32_bf16(al, bh, acc[nf], 0, 0, 0);
            acc[nf] = __builtin_amdgcn_mfma_f32_16x16x32_bf16(ah, bl, acc[nf], 0, 0, 0);
        }
        __builtin_amdgcn_s_setprio(0);
        #pragma unroll
        for (int k = 0; k < 8; ++k) xb[k] = xn[k];
    }
    const int cm = g * 4;
    #pragma unroll
    for (int nf = 0; nf < 4; ++nf) {
        int n = nf * 16 + rl;   // < 64
        float bb = b5[n];
        #pragma unroll
        for (int j = 0; j < 4; ++j)
            c1s[wave][cm + j][n] = leakyf(acc[nf][j] + bb);
    }
    // phase 2: K=64, N=8 (wave-local LDS; unpermuted)
    f32x4 acc2 = {0.f,0.f,0.f,0.f};
    #pragma unroll
    for (int s = 0; s < 2; ++s) {
        const int kk = s * 32 + g * 8;
        float4 p = *(const float4*)(&c1s[wave][rl][kk]);
        float4 q = *(const float4*)(&c1s[wave][rl][kk + 4]);
        float a2[8] = {p.x, p.y, p.z, p.w, q.x, q.y, q.z, q.w};
        bf16x8 ah, al;
        #pragma unroll
        for (int j = 0; j < 8; ++j) {
            short h = f2bf(a2[j]); ah[j] = h;
            al[j] = f2bf(a2[j] - bf2f(h));
        }
        const bf16x8 bh = *(const bf16x8*)(&s6h[rl][kk]);
        const bf16x8 bl = *(const bf16x8*)(&s6l[rl][kk]);
        acc2 = __builtin_amdgcn_mfma_f32_16x16x32_bf16(ah, bh, acc2, 0, 0, 0);
        acc2 = __builtin_amdgcn_mfma_f32_16x16x32_bf16(al, bh, acc2, 0, 0, 0);
        acc2 = __builtin_amdgcn_mfma_f32_16x16x32_bf16(ah, bl, acc2, 0, 0, 0);
    }
    if (rl < 8) {
        float bb = b6[rl];
        #pragma unroll
        for (int j = 0; j < 4; ++j) {
            float v = leakyf(acc2[j] + bb);
            C[(size_t)(m0 + cm + j) * 8 + rl] = v;
        }
    }
}

// BN finalize (permuted out): sbP[P(c)] = rstd*g, tbP[P(c)] = b - mean*rstd*g
// 128 blocks; c>=116 writes zeros (pad slots).
__global__ void bn_final_st_p(const float* __restrict__ statp, const float* __restrict__ g,
                              const float* __restrict__ bta, float* __restrict__ sbP,
                              float* __restrict__ tbP, int cnt)
{
    int c = blockIdx.x, tid = threadIdx.x;   // 128 x 256
    int pc = (c & 15) * 8 + (c >> 4);
    if (c >= ROIN) { if (tid == 0) { sbP[pc] = 0.f; tbP[pc] = 0.f; } return; }
    float a1 = 0.f, a2 = 0.f;
    for (int i = tid; i < cnt; i += 256) {
        a1 += statp[(size_t)c * cnt + i];
        a2 += statp[(size_t)(116 + c) * cnt + i];
    }
    __shared__ float r1[256], r2[256];
    r1[tid] = a1; r2[tid] = a2; __syncthreads();
    for (int off = 128; off > 0; off >>= 1) {
        if (tid < off) { r1[tid] += r1[tid + off]; r2[tid] += r2[tid + off]; }
        __syncthreads();
    }
    if (tid == 0) {
        float mean = r1[0] / (float)NROWS;
        float var = r2[0] / (float)NROWS - mean * mean;
        float rstd = 1.f / sqrtf(var + EPSBN);
        float s = rstd * g[c];
        sbP[pc] = s;
        tbP[pc] = bta[c] - mean * s;
    }
}

// sq[bz] = sum of 116 per-M-row sumsq partials
__global__ void sq_reduce(const float* __restrict__ rsq, float* __restrict__ sq)
{
    int i = blockIdx.x * 256 + threadIdx.x;
    if (i >= NBZ) return;
    const float* p = rsq + (size_t)i * ROIN;
    float s = 0.f;
    #pragma unroll 4
    for (int r = 0; r < ROIN; ++r) s += p[r];
    sq[i] = s;
}

// ---------------------------------------------------------------------------
// proj1 via bf16x2 MFMA, split-K over precomputed bf16 hi/lo xf
// (XH/XL [1024][14848] permuted; wt1 K-permuted to match).
// Bit-identical to the old fp32-read version: XH/XL hold exactly the
// f2bf splits the old kernel computed inline.
// ---------------------------------------------------------------------------
__global__ __launch_bounds__(256) void mfma_proj1(
    const short* __restrict__ XH, const short* __restrict__ XL,
    const short* __restrict__ wt_hi, const short* __restrict__ wt_lo,
    float* __restrict__ part)
{
    const int wave = threadIdx.x >> 6, lane = threadIdx.x & 63;
    const int m0 = blockIdx.x * 64 + wave * 16;
    const int rl = lane & 15, g = lane >> 4;
    const int kbase = blockIdx.z * PCH;
    const short* Ah = XH + (size_t)(m0 + rl) * SROW;
    const short* Al = XL + (size_t)(m0 + rl) * SROW;
    f32x4 acc[8];
    #pragma unroll
    for (int nf = 0; nf < 8; ++nf) acc[nf] = (f32x4){0.f,0.f,0.f,0.f};
    for (int s = 0; s < 16; ++s) {
        const int kk = kbase + s * 32 + g * 8;
        const bf16x8 ah = *(const bf16x8*)(Ah + kk);
        const bf16x8 al = *(const bf16x8*)(Al + kk);
        #pragma unroll
        for (int nf = 0; nf < 8; ++nf) {
            size_t boff = (size_t)(nf * 16 + rl) * W1LD + kk;
            bf16x8 bh = *(const bf16x8*)(wt_hi + boff);
            bf16x8 bl = *(const bf16x8*)(wt_lo + boff);
            acc[nf] = __builtin_amdgcn_mfma_f32_16x16x32_bf16(ah, bh, acc[nf], 0, 0, 0);
            acc[nf] = __builtin_amdgcn_mfma_f32_16x16x32_bf16(al, bh, acc[nf], 0, 0, 0);
            acc[nf] = __builtin_amdgcn_mfma_f32_16x16x32_bf16(ah, bl, acc[nf], 0, 0, 0);
        }
    }
    float* Cb = part + (size_t)blockIdx.z * NBZ * ROIN;
    const int cm = g * 4;
    #pragma unroll
    for (int nf = 0; nf < 8; ++nf) {
        int n = nf * 16 + rl;
        if (n < ROIN) {
            #pragma unroll
            for (int j = 0; j < 4; ++j)
                Cb[(size_t)(m0 + cm + j) * ROIN + n] = acc[nf][j];
        }
    }
}

// split-K reduce for proj1 (+bias +relu)
__global__ void proj_reduce(const float* __restrict__ ppart,
                            const float* __restrict__ bias, float* __restrict__ t1)
{
    int e = blockIdx.x * 256 + threadIdx.x;
    if (e >= NBZ * ROIN) return;
    int n = e % ROIN;
    float s = 0.f;
    for (int z = 0; z < PZ; ++z) s += ppart[(size_t)z * NBZ * ROIN + e];
    t1[e] = fmaxf(s + bias[n], 0.f);
}

// ---------------------------------------------------------------------------
// fp32 GEMM NT (sim = pn @ pn^T, K=116), symmetric mirror write
// ---------------------------------------------------------------------------
__global__ __launch_bounds__(256) void gemm_nt_sym(
    const float* __restrict__ A, float* __restrict__ C, int M, int K, float scale)
{
    if ((int)blockIdx.y < (int)blockIdx.x) return;
    __shared__ float As[16][65];
    __shared__ float Bs[16][65];
    const int tid = threadIdx.x;
    const int m0 = blockIdx.x * 64;
    const int n0 = blockIdx.y * 64;
    const int tm4 = (tid >> 4) * 4;
    const int tn4 = (tid & 15) * 4;
    const int rA  = tid >> 2;
    const int kbA = (tid & 3) * 4;
    float acc[4][4] = {};
    for (int kt = 0; kt < K; kt += 16) {
        int kg = kt + kbA;
        if (kg + 4 <= K) {
            float4 va = *(const float4*)(A + (size_t)(m0 + rA) * K + kg);
            As[kbA + 0][rA] = va.x; As[kbA + 1][rA] = va.y;
            As[kbA + 2][rA] = va.z; As[kbA + 3][rA] = va.w;
            float4 vb = *(const float4*)(A + (size_t)(n0 + rA) * K + kg);
            Bs[kbA + 0][rA] = vb.x; Bs[kbA + 1][rA] = vb.y;
            Bs[kbA + 2][rA] = vb.z; Bs[kbA + 3][rA] = vb.w;
        } else {
            #pragma unroll
            for (int kk = 0; kk < 4; ++kk) {
                int kgg = kg + kk;
                As[kbA + kk][rA] = (kgg < K) ? A[(size_t)(m0 + rA) * K + kgg] : 0.f;
                Bs[kbA + kk][rA] = (kgg < K) ? A[(size_t)(n0 + rA) * K + kgg] : 0.f;
            }
        }
        __syncthreads();
        #pragma unroll
        for (int k = 0; k < 16; ++k) {
            float a[4], b[4];
            #pragma unroll
            for (int i = 0; i < 4; ++i) a[i] = As[k][tm4 + i];
            #pragma unroll
            for (int j = 0; j < 4; ++j) b[j] = Bs[k][tn4 + j];
            #pragma unroll
            for (int i = 0; i < 4; ++i)
                #pragma unroll
                for (int j = 0; j < 4; ++j)
                    acc[i][j] = fmaf(a[i], b[j], acc[i][j]);
        }
        __syncthreads();
    }
    #pragma unroll
    for (int i = 0; i < 4; ++i) {
        int m = m0 + tm4 + i;
        #pragma unroll
        for (int j = 0; j < 4; ++j) {
            int n = n0 + tn4 + j;
            float v = acc[i][j] * scale;
            C[(size_t)m * M + n] = v;
            C[(size_t)n * M + m] = v;
        }
    }
}

// ---------------------------------------------------------------------------
// Gram via bf16 MFMA over padded/permuted xfh. 1D grid 576 = 36 tri x 16 z,
// XCD-affine: wg = (id&7)*72 + (id>>3).
// ---------------------------------------------------------------------------
__global__ __launch_bounds__(256) void gram_mfma(
    const short* __restrict__ Xh, float* __restrict__ gpart)
{
    const int id = blockIdx.x;
    const int wg = (id & 7) * 72 + (id >> 3);
    const int z = wg / 36;
    const int tri = wg - z * 36;
    int bx = 0;
    #pragma unroll
    for (int b = 1; b < 8; ++b) {
        int base = b * 8 - (b * (b - 1)) / 2;
        if (base <= tri) bx = b;
    }
    const int by = tri - (bx * 8 - (bx * (bx - 1)) / 2) + bx;
    const int k0 = z * GRAMKS;
    const int wave = threadIdx.x >> 6, lane = threadIdx.x & 63;
    const int wr = wave >> 1, wc = wave & 1;
    const int row = lane & 15, koff = (lane >> 4) * 8;
    const short* Ap[4]; const short* Bp[4];
    #pragma unroll
    for (int i = 0; i < 4; ++i) {
        Ap[i] = Xh + (size_t)(bx * 128 + wr * 64 + i * 16 + row) * SROW;
        Bp[i] = Xh + (size_t)(by * 128 + wc * 64 + i * 16 + row) * SROW;
    }
    f32x4 acc[4][4];
    #pragma unroll
    for (int i = 0; i < 4; ++i)
        #pragma unroll
        for (int j = 0; j < 4; ++j) acc[i][j] = (f32x4){0.f,0.f,0.f,0.f};
    bf16x8 a[4], b[4];
    {
        int kk = k0 + koff;
        #pragma unroll
        for (int i = 0; i < 4; ++i) {
            a[i] = *(const bf16x8*)(Ap[i] + kk);
            b[i] = *(const bf16x8*)(Bp[i] + kk);
        }
    }
    for (int k = k0 + 32; k < k0 + GRAMKS; k += 32) {
        bf16x8 an[4], bn[4];
        int kk = k + koff;
        #pragma unroll
        for (int i = 0; i < 4; ++i) {
            an[i] = *(const bf16x8*)(Ap[i] + kk);
            bn[i] = *(const bf16x8*)(Bp[i] + kk);
        }
        #pragma unroll
        for (int i = 0; i < 4; ++i)
            #pragma unroll
            for (int j = 0; j < 4; ++j)
                acc[i][j] = __builtin_amdgcn_mfma_f32_16x16x32_bf16(a[i], b[j], acc[i][j], 0, 0, 0);
        #pragma unroll
        for (int i = 0; i < 4; ++i) { a[i] = an[i]; b[i] = bn[i]; }
    }
    #pragma unroll
    for (int i = 0; i < 4; ++i)
        #pragma unroll
        for (int j = 0; j < 4; ++j)
            acc[i][j] = __builtin_amdgcn_mfma_f32_16x16x32_bf16(a[i], b[j], acc[i][j], 0, 0, 0);
    float* Cb = gpart + ((size_t)z * NTRI + tri) * 16384;
    const int crow = (lane >> 4) * 4;
    const int ccol = lane & 15;
    #pragma unroll
    for (int i = 0; i < 4; ++i) {
        #pragma unroll
        for (int j = 0; j < 4; ++j) {
            int cl = wc * 64 + j * 16 + ccol;
            #pragma unroll
            for (int jj = 0; jj < 4; ++jj) {
                int rl2 = wr * 64 + i * 16 + crow + jj;
                Cb[(size_t)rl2 * 128 + cl] = acc[i][j][jj];
            }
        }
    }
}

// reduce GRAMZ packed-tri partials -> fused dist (with mirror write)
__global__ void gram_reduce_dist(const float* __restrict__ gpart,
                                 const float* __restrict__ sim, const float* __restrict__ sq,
                                 const int* __restrict__ ages, const int* __restrict__ genders,
                                 const float* __restrict__ fscal, float* __restrict__ G)
{
    const int t = blockIdx.x;   // 0..35
    int bx = 0;
    #pragma unroll
    for (int b = 1; b < 8; ++b) {
        int base = b * 8 - (b * (b - 1)) / 2;
        if (base <= t) bx = b;
    }
    const int by = t - (bx * 8 - (bx * (bx - 1)) / 2) + bx;
    int e = blockIdx.y * 1024 + threadIdx.x * 4;
    float sx = 0.f, sy = 0.f, sz = 0.f, sw = 0.f;
    for (int z = 0; z < GRAMZ; ++z) {
        float4 v = *(const float4*)(gpart + ((size_t)z * NTRI + t) * 16384 + e);
        sx += v.x; sy += v.y; sz += v.z; sw += v.w;
    }
    const int i = bx * 128 + (e >> 7), j0 = by * 128 + (e & 127);
    const float smin = fscal[0], smax = fscal[1];
    const float inv = 1.f / (smax - smin);
    const float sqi = sq[i];
    const int agei = ages[i], geni = genders[i];
    float4 simv = *(const float4*)(sim + ((size_t)i << 10) + j0);
    float gs[4] = {sx, sy, sz, sw};
    float sms[4] = {simv.x, simv.y, simv.z, simv.w};
    float out[4];
    #pragma unroll
    for (int c = 0; c < 4; ++c) {
        int j = j0 + c;
        float sn = (sms[c] - smin) * inv;
        float d2 = fmaxf(sqi + sq[j] - 2.f * gs[c], 0.f);
        float fs = expf(-ALPHA * sqrtf(d2));
        float total = fs * (1.f - sn) + sn;
        int da = agei - ages[j]; if (da < 0) da = -da;
        bool cond = (da <= BETAC) && (geni == genders[j]);
        out[c] = total * (cond ? ACOEF : 1.f - ACOEF);
    }
    float4 o = {out[0], out[1], out[2], out[3]};
    *(float4*)(G + ((size_t)i << 10) + j0) = o;
    #pragma unroll
    for (int c = 0; c < 4; ++c)
        G[((size_t)(j0 + c) << 10) + i] = out[c];
}

// p[1024,116] -> row L2-normalize in place
__global__ void rownorm(float* __restrict__ p)
{
    int row = blockIdx.x, t = threadIdx.x;   // 128 threads
    __shared__ float red[128];
    float x = 0.f, v = 0.f;
    if (t < ROIN) { x = p[row * ROIN + t]; v = x * x; }
    red[t] = v; __syncthreads();
    for (int off = 64; off > 0; off >>= 1) { if (t < off) red[t] += red[t + off]; __syncthreads(); }
    float inv = 1.f / sqrtf(red[0]);
    if (t < ROIN) p[row * ROIN + t] = x * inv;
}

// global min/max of sim
__global__ void minmax_part(const float* __restrict__ sim, float* __restrict__ mm)
{
    int t = threadIdx.x, b = blockIdx.x;   // 512 x 256
    float mn = 1e30f, mx = -1e30f;
    for (size_t i = (size_t)b * 256 + t; i < 1048576u; i += 512u * 256u) {
        float v = sim[i]; mn = fminf(mn, v); mx = fmaxf(mx, v);
    }
    __shared__ float smn[256], smx[256];
    smn[t] = mn; smx[t] = mx; __syncthreads();
    for (int off = 128; off > 0; off >>= 1) {
        if (t < off) { smn[t] = fminf(smn[t], smn[t + off]); smx[t] = fmaxf(smx[t], smx[t + off]); }
        __syncthreads();
    }
    if (t == 0) { mm[b] = smn[0]; mm[512 + b] = smx[0]; }
}
__global__ void minmax_final(const float* __restrict__ mm, float* __restrict__ fscal)
{
    int t = threadIdx.x;   // 512 threads
    __shared__ float smn[512], smx[512];
    smn[t] = mm[t]; smx[t] = mm[512 + t]; __syncthreads();
    for (int off = 256; off > 0; off >>= 1) {
        if (t < off) { smn[t] = fminf(smn[t], smn[t + off]); smx[t] = fmaxf(smx[t], smx[t + off]); }
        __syncthreads();
    }
    if (t == 0) { fscal[0] = smn[0]; fscal[1] = smx[0]; }
}

// labels[i] = argmax(site[i,0..3]) (first max)
__global__ void labels_k(const int* __restrict__ site, int* __restrict__ labels)
{
    int i = blockIdx.x * 256 + threadIdx.x;
    if (i >= NBZ) return;
    int best = site[4 * i], bi = 0;
    #pragma unroll
    for (int k = 1; k < 4; ++k) { int v = site[4 * i + k]; if (v > best) { best = v; bi = k; } }
    labels[i] = bi;
}

__global__ void rowcnt_k(const int* __restrict__ labels, int* __restrict__ rowcnt)
{
    int i = blockIdx.x * 256 + threadIdx.x;
    if (i >= NBZ) return;
    int li = labels[i], c = 0;
    for (int j = 0; j < NBZ; ++j) c += (labels[j] == li);
    rowcnt[i] = c;
}

// exclusive scan of per-row positive counts; iscal[0]=npos, iscal[1]=m
__global__ __launch_bounds__(1024) void scan_k(const int* __restrict__ rowcnt,
                                               int* __restrict__ rowoff, int* __restrict__ iscal)
{
    __shared__ int s[1024];
    int t = threadIdx.x;
    int c = rowcnt[t];
    s[t] = c; __syncthreads();
    for (int off = 1; off < 1024; off <<= 1) {
        int v = (t >= off) ? s[t - off] : 0;
        __syncthreads();
        s[t] += v;
        __syncthreads();
    }
    rowoff[t] = s[t] - c;
    if (t == 1023) {
        int npos = s[1023];
        int nneg = 1024 * 1024 - npos;
        iscal[0] = npos;
        iscal[1] = (npos < nneg) ? npos : nneg;
    }
}

// scatter sim values to rank-paired pos/neg arrays
__global__ void pair_scatter(const int* __restrict__ labels, const int* __restrict__ rowoff,
                             const int* __restrict__ iscal, const float* __restrict__ sim,
                             float* __restrict__ posval, float* __restrict__ negval)
{
    int row = blockIdx.x, t = threadIdx.x;
    int m = iscal[1];
    int li = labels[row];
    int j0 = t * 4;
    int eq[4]; int c = 0;
    #pragma unroll
    for (int kk = 0; kk < 4; ++kk) { eq[kk] = (labels[j0 + kk] == li); c += eq[kk]; }
    __shared__ int s[256];
    s[t] = c; __syncthreads();
    for (int off = 1; off < 256; off <<= 1) {
        int v = (t >= off) ? s[t - off] : 0;
        __syncthreads();
        s[t] += v;
        __syncthreads();
    }
    int r = rowoff[row] + s[t] - c;
    size_t base = (size_t)row * 1024;
    #pragma unroll
    for (int kk = 0; kk < 4; ++kk) {
        size_t f = base + j0 + kk;
        float v = sim[f];
        if (eq[kk]) { if (r < m) posval[r] = v; r++; }
        else { long nr = (long)f - r; if (nr < m) negval[nr] = v; }
    }
}

__global__ void loss_part(const float* __restrict__ posval, const float* __restrict__ negval,
                          const int* __restrict__ iscal, float* __restrict__ lp)
{
    int m = iscal[1];
    int t = threadIdx.x, b = blockIdx.x;   // 1024 x 256
    float s = 0.f;
    for (int k = b * 256 + t; k < m; k += 1024 * 256) {
        float d = negval[k] - posval[k];
        s += fmaxf(d, 0.f) + log1pf(expf(-fabsf(d)));
    }
    __shared__ float red[256];
    red[t] = s; __syncthreads();
    for (int off = 128; off > 0; off >>= 1) { if (t < off) red[t] += red[t + off]; __syncthreads(); }
    if (t == 0) lp[b] = red[0];
}

__global__ void loss_final(const float* __restrict__ lp, const int* __restrict__ iscal,
                           float* __restrict__ outp)
{
    int t = threadIdx.x;   // 256
    double s = 0.0;
    for (int k = t; k < 1024; k += 256) s += (double)lp[k];
    __shared__ double red[256];
    red[t] = s; __syncthreads();
    for (int off = 128; off > 0; off >>= 1) { if (t < off) red[t] += red[t + off]; __syncthreads(); }
    if (t == 0) {
        int m = iscal[1]; if (m < 1) m = 1;
        outp[0] = (float)(red[0] / (double)m);
    }
}

// row-wise top-8 (ties -> lower index)
__global__ void topk8(const float* __restrict__ dist, float* __restrict__ topv, int* __restrict__ topi)
{
    int row = blockIdx.x, t = threadIdx.x;
    __shared__ float sv[1024];
    __shared__ float rv[256];
    __shared__ int   ri[256];
    for (int j = t; j < 1024; j += 256) sv[j] = dist[(size_t)row * 1024 + j];
    __syncthreads();
    for (int k = 0; k < 8; ++k) {
        float bv = -1e30f; int bi = 1 << 20;
        for (int j = t; j < 1024; j += 256) {
            float x = sv[j];
            if (x > bv || (x == bv && j < bi)) { bv = x; bi = j; }
        }
        rv[t] = bv; ri[t] = bi;
        __syncthreads();
        for (int s = 128; s > 0; s >>= 1) {
            if (t < s) {
                float ov = rv[t + s]; int oi = ri[t + s];
                if (ov > rv[t] || (ov == rv[t] && oi < ri[t])) { rv[t] = ov; ri[t] = oi; }
            }
            __syncthreads();
        }
        if (t == 0) { topv[row * 8 + k] = rv[0]; topi[row * 8 + k] = ri[0]; sv[ri[0]] = -1e30f; }
        __syncthreads();
    }
}

// bn3: per-ROI-channel stats over (N=1024, L=8); writes final output
__global__ void bn3_k(const float* __restrict__ X, const float* __restrict__ g,
                      const float* __restrict__ bta, float* __restrict__ out)
{
    int c = blockIdx.x, t = threadIdx.x;   // 116 x 256
    float s = 0.f, s2 = 0.f;
    for (int k = t; k < 8192; k += 256) {
        int n = k >> 3, l = k & 7;
        float v = X[(size_t)n * 928 + c * 8 + l];
        s += v; s2 += v * v;
    }
    __shared__ float rs[256], rs2[256];
    rs[t] = s; rs2[t] = s2; __syncthreads();
    for (int off = 128; off > 0; off >>= 1) {
        if (t < off) { rs[t] += rs[t + off]; rs2[t] += rs2[t + off]; }
        __syncthreads();
    }
    __shared__ float sm, sr;
    if (t == 0) {
        float mean = rs[0] / 8192.f;
        float var = rs2[0] / 8192.f - mean * mean;
        sm = mean; sr = 1.f / sqrtf(var + EPSBN);
    }
    __syncthreads();
    float mean = sm, rstd = sr, gg = g[c], bb = bta[c];
    for (int k = t; k < 8192; k += 256) {
        int n = k >> 3, l = k & 7;
        size_t idx = (size_t)n * 928 + c * 8 + l;
        out[idx] = (X[idx] - mean) * rstd * gg + bb;
    }
}

// ---------------------------------------------------------------------------
extern "C" void kernel_launch(void* const* d_in, const int* in_sizes, int n_in,
                              void* d_out, int out_size, void* d_ws, size_t ws_size,
                              hipStream_t stream)
{
    const float* x        = (const float*)d_in[0];
    const float* pseudo   = (const float*)d_in[1];
    const int*   ages     = (const int*)d_in[2];
    const int*   genders  = (const int*)d_in[3];
    const int*   site     = (const int*)d_in[4];
    const float* fc_p_w   = (const float*)d_in[5];
    const float* fc_p_b   = (const float*)d_in[6];
    const float* proj_w1  = (const float*)d_in[7];
    const float* proj_b1  = (const float*)d_in[8];
    const float* proj_w2  = (const float*)d_in[9];
    const float* proj_b2  = (const float*)d_in[10];
    const float* gcn_w1   = (const float*)d_in[11];
    const float* gcn_b1   = (const float*)d_in[12];
    const float* gcn_w2   = (const float*)d_in[13];
    const float* gcn_b2   = (const float*)d_in[14];
    const float* gcn1_w   = (const float*)d_in[15];
    const float* gcn1_b   = (const float*)d_in[16];
    const float* gcn2_w1  = (const float*)d_in[17];
    const float* gcn2_b1  = (const float*)d_in[18];
    const float* gcn2_w2  = (const float*)d_in[19];
    const float* gcn2_b2  = (const float*)d_in[20];
    const float* bn1_g    = (const float*)d_in[21];
    const float* bn1_b    = (const float*)d_in[22];
    const float* bn2_g    = (const float*)d_in[23];
    const float* bn2_b    = (const float*)d_in[24];
    const float* bn3_g    = (const float*)d_in[25];
    const float* bn3_b    = (const float*)d_in[26];
    float* dout = (float*)d_out;

    char* w = (char*)d_ws;
    size_t off = 0;
    auto carve = [&](size_t bytes) { char* p = w + off; off = (off + bytes + 255) & ~(size_t)255; return p; };
    float* xfb    = (float*)carve((size_t)NROWS * LDF * 4);   // 60.8 MB: xfh+xfl bf16
    float* hA     = (float*)carve((size_t)NROWS * LDF * 4);
    float* hB     = (float*)carve((size_t)NROWS * LDF * 4);
    float* G      = (float*)carve(1048576u * 4);
    float* simb   = (float*)carve(1048576u * 4);
    float* t1     = (float*)carve((size_t)NBZ * ROIN * 4);
    float* pbuf   = (float*)carve((size_t)NBZ * ROIN * 4);
    float* sq     = (float*)carve(4096);
    float* rsq    = (float*)carve((size_t)NROWS * 4);
    int*   labels = (int*)carve(4096);
    int*   rowcnt = (int*)carve(4096);
    int*   rowoff = (int*)carve(4096);
    int*   iscal  = (int*)carve(256);
    float* fscal  = (float*)carve(256);
    float* posval = (float*)carve(524288u * 4);
    float* negval = (float*)carve(524288u * 4);
    float* lpart  = (float*)carve(4096);
    float* mmpart = (float*)carve(4096);
    float* topv   = (float*)carve(32768);
    int*   topi   = (int*)carve(32768);
    float* statp  = (float*)carve((size_t)232 * GX2 * 4);
    float* sbAp   = (float*)carve(512);
    float* tbAp   = (float*)carve(512);
    float* sbBp   = (float*)carve(512);
    float* tbBp   = (float*)carve(512);
    short* wt1_hi = (short*)carve((size_t)128 * W1LD * 2);    // 3.8 MB
    short* wt1_lo = (short*)carve((size_t)128 * W1LD * 2);
    short* wts    = (short*)carve((size_t)7 * 2 * 16384 * 2);
    // xf region holds the bf16 hi/lo split (exactly fills it):
    short* xfh    = (short*)xfb;                        // 30.4 MB, alive until wg1 done
    short* xfl    = (short*)xfb + (size_t)NROWS * LDF;  // 30.4 MB, dead after proj1
    // aliases into dead phases:
    float* ppart  = hA;                                 // proj1 partials (13.8 MB)
    float* gpart  = hA;                                 // Gram partials 16*36*64KB = 37.7 MB
    short* actH1  = (short*)hA;                         // 29.7 MB (gpart dead)
    short* actH2  = (short*)hB;                         // 29.7 MB (hB free)
    short* actH3  = (short*)hA;                         // 29.7 MB (actH1 dead)
    float* h45    = hB;                                 // 3.8 MB (actH2 dead)

    auto wt_hi = [&](int i) { return wts + (size_t)i * 2 * 16384; };
    auto wt_lo = [&](int i) { return wts + (size_t)i * 2 * 16384 + 16384; };

    // 0. weight pretranspose + hi/lo split (PERM for bf16-permuted-A consumers)
    wt1_conv<<<(128 * W1LD) / 256, 256, 0, stream>>>(proj_w1, wt1_hi, wt1_lo);
    wt_conv<false><<<64, 256, 0, stream>>>(fc_p_w,  wt_hi(0), wt_lo(0), 116, 116);
    wt_conv<false><<<64, 256, 0, stream>>>(proj_w2, wt_hi(1), wt_lo(1), 116, 116);
    wt_conv<true ><<<64, 256, 0, stream>>>(gcn_w1,  wt_hi(2), wt_lo(2), 116, 116);
    wt_conv<true ><<<64, 256, 0, stream>>>(gcn_w2,  wt_hi(3), wt_lo(3), 116, 116);
    wt_conv<true ><<<64, 256, 0, stream>>>(gcn1_w,  wt_hi(4), wt_lo(4), 116, 116);
    wt_conv<true ><<<64, 256, 0, stream>>>(gcn2_w1, wt_hi(5), wt_lo(5), 116, 64);
    wt_conv<false><<<64, 256, 0, stream>>>(gcn2_w2, wt_hi(6), wt_lo(6), 64, 8);

    // 1. xf = x + leaky(pseudo @ fc_p_w + b) -> permuted bf16 hi/lo + row sumsq
    mfma_gemm_w<4, 1, false><<<GX2, 512, 0, stream>>>(pseudo, wt_hi(0), wt_lo(0), fc_p_b, x,
                                                      nullptr, xfh, xfl, rsq, ROIN, LDF);
    sq_reduce<<<4, 256, 0, stream>>>(rsq, sq);

    // 2. proj head (bf16 hi/lo inputs; bit-identical to fp32-read version)
    mfma_proj1<<<dim3(16, 1, PZ), 256, 0, stream>>>(xfh, xfl, wt1_hi, wt1_lo, ppart);
    proj_reduce<<<(NBZ * ROIN + 255) / 256, 256, 0, stream>>>(ppart, proj_b1, t1);
    mfma_gemm_w<1, 0, false><<<8, 512, 0, stream>>>(t1, wt_hi(1), wt_lo(1), proj_b2, nullptr, pbuf,
                                                    nullptr, nullptr, nullptr, ROIN, ROIN);
    rownorm<<<NBZ, 128, 0, stream>>>(pbuf);

    // 3. sim = (pn @ pn^T) / TEMP
    gemm_nt_sym<<<dim3(16, 16, 1), 256, 0, stream>>>(pbuf, simb, NBZ, ROIN, 1.f / 0.07f);

    // 4. contrastive loss
    labels_k<<<4, 256, 0, stream>>>(site, labels);
    rowcnt_k<<<4, 256, 0, stream>>>(labels, rowcnt);
    scan_k<<<1, 1024, 0, stream>>>(rowcnt, rowoff, iscal);
    pair_scatter<<<NBZ, 256, 0, stream>>>(labels, rowoff, iscal, simb, posval, negval);
    loss_part<<<1024, 256, 0, stream>>>(posval, negval, iscal, lpart);
    loss_final<<<1, 256, 0, stream>>>(lpart, iscal, dout + (size_t)NBZ * ROIN * 8);

    // 5. sim min/max, Gram (XCD-affine), fused reduce+dist, top-k
    minmax_part<<<512, 256, 0, stream>>>(simb, mmpart);
    minmax_final<<<1, 512, 0, stream>>>(mmpart, fscal);
    gram_mfma<<<NTRI * GRAMZ, 256, 0, stream>>>(xfh, gpart);
    gram_reduce_dist<<<dim3(NTRI, 16), 256, 0, stream>>>(gpart, simb, sq, ages, genders, fscal, G);
    topk8<<<NBZ, 256, 0, stream>>>(G, topv, topi);

    // 6. GCN stack on bf16-permuted activations (weights & BN vectors permuted)
    mfma_gemm_wg_h<0, false><<<GX2, 512, 0, stream>>>(topv, topi, xfh, nullptr, nullptr,
                                                      wt_hi(2), wt_lo(2), gcn_b1, actH1, nullptr);
    mfma_gemm_bA<<<GX2, 512, 0, stream>>>(actH1, wt_hi(3), wt_lo(3), gcn_b2, actH2, statp);
    bn_final_st_p<<<128, 256, 0, stream>>>(statp, bn1_g, bn1_b, sbAp, tbAp, GX2);

    mfma_gemm_wg_h<2, true><<<GX2, 512, 0, stream>>>(topv, topi, actH2, sbAp, tbAp,
                                                     wt_hi(4), wt_lo(4), gcn1_b, actH3, statp);
    bn_final_st_p<<<128, 256, 0, stream>>>(statp, bn2_g, bn2_b, sbBp, tbBp, GX2);

    mfma_gemm45_wg_h<<<GX45, 256, 0, stream>>>(topv, topi, actH3, sbBp, tbBp,
                                               wt_hi(5), wt_lo(5), gcn2_b1,
                                               wt_hi(6), wt_lo(6), gcn2_b2, h45);

    // 7. bn3 -> d_out
    bn3_k<<<116, 256, 0, stream>>>(h45, bn3_g, bn3_b, dout);
}